// Round 9
// baseline (2816.368 us; speedup 1.0000x reference)
//
#include <hip/hip_runtime.h>
#include <hip/hip_bf16.h>
#include <stdint.h>
#include <stddef.h>

// ---------------------------------------------------------------------------
// GRUEncoder: x[256,512,25,3] f32 -> 2-layer GRU(H=256) -> fc(hT) -> [256,256] f32
//
// Fused pipelined schedule (chunk = TC steps, 2-chunk layer skew):
//   cast_x ; cast_w ; gemm0(chunk0)
//   for i in 0..nc+1:   ONE launch: [scan L0 chunk i] || [scan L1 chunk i-2]
//                                   || [gemm0 chunk i+1] || [gemm1 chunk i-1]
//   cast_h ; fc gemm
//
// r9 structural change: FULL W_hh register residency via 4-wave WGs.
// The per-SIMD register file is 512 regs/lane; an 8-wave WG caps lanes at
// 256 total (r,z in 128 AGPR + n streamed from LDS = the 2300cy/step pole).
// A 4-wave WG at 1 wave/SIMD allows 512/lane:
//   wave owns hidden cols [w*64,+64) of ALL gates = 96 frags = 384 regs:
//     z,n -> 256 AGPR ("a"-pinned), r -> 128 VGPR ("v"-pinned)
//   working set ~115 arch  => ~245 arch + 256 agpr <= 512, no spill
// The n-gate LDS stream is GONE; LDS/step = 8 hbuf + 4 bias reads per wave.
// Scan geometry unchanged otherwise (16 WGs/layer x 16 batch rows, XOR-
// swizzled double hbuf, one lgkm-only barrier/step, xg prefetch in flight).
// Fused gemms become 4-wave 256x384-tile bodies (1 wave/SIMD kernel-wide).
// ---------------------------------------------------------------------------

typedef _Float16 f16;
typedef _Float16 f16x8 __attribute__((ext_vector_type(8)));
typedef _Float16 f16x4 __attribute__((ext_vector_type(4)));
typedef float    f32x4 __attribute__((ext_vector_type(4)));

#define B_      256
#define T_      512
#define H_      256
#define G_      768      // 3*H
#define IN_RAW  75
#define KX      96       // padded input K
#define MROWS   (T_*B_)  // 131072

__device__ __forceinline__ float rcp_(float x){ return __builtin_amdgcn_rcpf(x); }
__device__ __forceinline__ float sigm(float x){ return rcp_(1.f + __expf(-x)); }
__device__ __forceinline__ float tanh_(float x){ return 1.f - 2.f*rcp_(1.f + __expf(2.f*x)); }

// barrier that waits ONLY on LDS ops (no vmcnt/expcnt drain).
__device__ __forceinline__ void bar_lds(){
  asm volatile("s_waitcnt lgkmcnt(0)" ::: "memory");
  __builtin_amdgcn_s_barrier();
  __builtin_amdgcn_sched_barrier(0);   // no hoisting of LDS reads above barrier
}

// --------------------------------------------------------------------------
// cast_x: x[b][t][j] (f32) -> xb[t*256+b][96] (fp16, j>=75 zero)
// --------------------------------------------------------------------------
__global__ __launch_bounds__(256) void cast_x(const float* __restrict__ x,
                                              f16* __restrict__ xb){
  int idx = blockIdx.x*256 + threadIdx.x;        // grid*256 == 131072*96 exact
  int row = idx / KX;
  int j   = idx - row*KX;
  int t   = row >> 8;        // row = t*256 + b
  int b   = row & 255;
  float v = (j < IN_RAW) ? x[((size_t)b*T_ + t)*IN_RAW + j] : 0.f;
  xb[idx] = (f16)v;
}

// --------------------------------------------------------------------------
// cast_w: all weight casts + fused biases. grid*256 == 730624 exact.
// --------------------------------------------------------------------------
__global__ __launch_bounds__(256) void cast_w(
    const float* __restrict__ Wih0, const float* __restrict__ Whh0,
    const float* __restrict__ Wih1, const float* __restrict__ Whh1,
    const float* __restrict__ fcW,
    const float* __restrict__ bih0, const float* __restrict__ bhh0,
    const float* __restrict__ bih1, const float* __restrict__ bhh1,
    f16* __restrict__ W0h, f16* __restrict__ Whh0h, f16* __restrict__ Wih1h,
    f16* __restrict__ Whh1h, f16* __restrict__ fcWh,
    float* __restrict__ bias0, float* __restrict__ bias1){
  int i = blockIdx.x*256 + threadIdx.x;
  if (i < 73728){ int r = i/KX, j = i - r*KX;
    W0h[i] = (f16)((j < IN_RAW) ? Wih0[r*IN_RAW + j] : 0.f); return; }
  i -= 73728;
  if (i < 196608){ Whh0h[i] = (f16)Whh0[i]; return; } i -= 196608;
  if (i < 196608){ Wih1h[i] = (f16)Wih1[i]; return; } i -= 196608;
  if (i < 196608){ Whh1h[i] = (f16)Whh1[i]; return; } i -= 196608;
  if (i < 65536){ fcWh[i] = (f16)fcW[i]; return; } i -= 65536;
  if (i < 768){ bias0[i] = bih0[i] + (i < 512 ? bhh0[i] : 0.f); return; } i -= 768;
  if (i < 768){ bias1[i] = bih1[i] + (i < 512 ? bhh1[i] : 0.f); }
}

// --------------------------------------------------------------------------
// cast_h: h1s f32 [256*256] -> hT fp16
// --------------------------------------------------------------------------
__global__ __launch_bounds__(256) void cast_h(const float* __restrict__ hs,
                                              f16* __restrict__ hT){
  int i = blockIdx.x*256 + threadIdx.x;
  hT[i] = (f16)hs[i];
}

// --------------------------------------------------------------------------
// gemm_k: out[M,N] = A[M,K](fp16) @ W[N,K]^T(fp16) + bias. 256-thread/8-wave
// standalone kernel for the prologue gemm and the fc epilogue.
// --------------------------------------------------------------------------
template<int K, int BN, bool OUTF32>
__global__ __launch_bounds__(256, 2) void gemm_k(const f16* __restrict__ A,
    const f16* __restrict__ W, const float* __restrict__ bias,
    void* __restrict__ outp, const int N){
  constexpr int NT = BN/16;
  const int tid  = threadIdx.x;
  const int wave = tid >> 6, lane = tid & 63;
  const int quad = lane >> 4, l16 = lane & 15;
  const long mbase = (long)blockIdx.x*128 + wave*32;
  const int  nbase = blockIdx.y*BN;
  f32x4 acc[2][NT] = {};
#pragma unroll 2
  for (int kc = 0; kc < K/32; ++kc){
    f16x8 a0 = *(const f16x8*)(A + (mbase +      l16)*K + kc*32 + quad*8);
    f16x8 a1 = *(const f16x8*)(A + (mbase + 16 + l16)*K + kc*32 + quad*8);
#pragma unroll
    for (int nt = 0; nt < NT; ++nt){
      f16x8 b = *(const f16x8*)(W + (long)(nbase + nt*16 + l16)*K + kc*32 + quad*8);
      acc[0][nt] = __builtin_amdgcn_mfma_f32_16x16x32_f16(a0, b, acc[0][nt], 0, 0, 0);
      acc[1][nt] = __builtin_amdgcn_mfma_f32_16x16x32_f16(a1, b, acc[1][nt], 0, 0, 0);
    }
  }
#pragma unroll
  for (int nt = 0; nt < NT; ++nt){
    const int col = nbase + nt*16 + l16;
    const float bv = bias[col];
#pragma unroll
    for (int af = 0; af < 2; ++af){
#pragma unroll
      for (int r = 0; r < 4; ++r){
        const long row = mbase + af*16 + quad*4 + r;   // D row = quad*4 + reg
        float v = acc[af][nt][r] + bv;
        if (OUTF32) ((float*)outp)[row*(long)N + col] = v;
        else        ((f16*)outp)[row*(long)N + col] = (f16)v;
      }
    }
  }
}

// --------------------------------------------------------------------------
// gemm_body4: 256-thread (4-wave) GEMM tile for the fused kernel.
// Block covers 256 rows (2 sequential 128-row tiles) x 384 cols, N=768.
// acc = 2x24 f32x4 = 192 regs -- fine at the fused kernel's 1-wave/SIMD
// allocation (up to 512 regs/lane).
// --------------------------------------------------------------------------
template<int K>
__device__ __forceinline__ void gemm_body4(const f16* __restrict__ A,
    const f16* __restrict__ W, const float* __restrict__ bias,
    f16* __restrict__ out, const int bx, const int by){
  const int tid  = threadIdx.x;
  const int wave = tid >> 6, lane = tid & 63;
  const int quad = lane >> 4, l16 = lane & 15;
  const int nbase = by*384;
#pragma unroll
  for (int mt = 0; mt < 2; ++mt){
    const long mbase = (long)bx*256 + mt*128 + wave*32;
    f32x4 acc[2][24] = {};
#pragma unroll 1
    for (int kc = 0; kc < K/32; ++kc){
      f16x8 a0 = *(const f16x8*)(A + (mbase +      l16)*K + kc*32 + quad*8);
      f16x8 a1 = *(const f16x8*)(A + (mbase + 16 + l16)*K + kc*32 + quad*8);
#pragma unroll
      for (int nt = 0; nt < 24; ++nt){
        f16x8 b = *(const f16x8*)(W + (long)(nbase + nt*16 + l16)*K + kc*32 + quad*8);
        acc[0][nt] = __builtin_amdgcn_mfma_f32_16x16x32_f16(a0, b, acc[0][nt], 0, 0, 0);
        acc[1][nt] = __builtin_amdgcn_mfma_f32_16x16x32_f16(a1, b, acc[1][nt], 0, 0, 0);
      }
    }
#pragma unroll
    for (int nt = 0; nt < 24; ++nt){
      const int col = nbase + nt*16 + l16;
      const float bv = bias[col];
#pragma unroll
      for (int af = 0; af < 2; ++af)
#pragma unroll
        for (int r = 0; r < 4; ++r)
          out[(mbase + af*16 + quad*4 + r)*(long)G_ + col] = (f16)(acc[af][nt][r] + bv);
    }
  }
}

// --------------------------------------------------------------------------
// scan_body: TC steps of one GRU layer; 4-wave WG, FULL weight residency.
// 16 WGs x 256 thr; WG owns batch rows [bx*16,+16).
// D[gate rows x batch cols] = Whh(A, register) * h(B, from swizzled hbuf).
// Wave owns hidden cols [w*64,+64) of r/z/n: 12 D-tiles, 96 MFMA/step.
//   z,n: 64 frags = 256 AGPR ("a"-pinned);  r: 32 frags = 128 VGPR ("v").
// hbuf: row*512 + ((chunk ^ (row&7))<<4), double-buffered; ONE lgkm-only
// barrier/step. xg(t+1) prefetched into cur, in flight across the barrier.
// --------------------------------------------------------------------------
__device__ __forceinline__ void scan_body(const f16* __restrict__ xg,
    const f16* __restrict__ Whh, const float* __restrict__ bhh,
    float* __restrict__ hstate, f16* __restrict__ out0,
    const int TC, const int bx){
  __shared__ char  hbufB[2][8192];     // 16 KB: h(t) fp16, XOR-swizzled
  __shared__ float bnlds[256];         // n-gate hidden bias
  const int tid  = threadIdx.x;        // 0..255
  const int wave = tid >> 6, lane = tid & 63;
  const int quad = lane >> 4, l16 = lane & 15;
  const int b0   = bx*16;
  const int jj   = wave*64 + quad*4;   // hidden col base; s*16 adds, s in 0..3

  // weights: wave owns hidden cols [wave*64,+64) of each gate.
  // Load+pin z,n into AGPR first (frees VGPRs as we go), then r into VGPR.
  f16x8 wz[4][8], wn[4][8], wr[4][8];
#pragma unroll
  for (int s = 0; s < 4; ++s)
#pragma unroll
    for (int kc = 0; kc < 8; ++kc){
      wz[s][kc] = *(const f16x8*)(Whh + (size_t)(256 + wave*64 + s*16 + l16)*H_ + kc*32 + quad*8);
      asm volatile("" : "+a"(wz[s][kc]));
    }
#pragma unroll
  for (int s = 0; s < 4; ++s)
#pragma unroll
    for (int kc = 0; kc < 8; ++kc){
      wn[s][kc] = *(const f16x8*)(Whh + (size_t)(512 + wave*64 + s*16 + l16)*H_ + kc*32 + quad*8);
      asm volatile("" : "+a"(wn[s][kc]));
    }
#pragma unroll
  for (int s = 0; s < 4; ++s)
#pragma unroll
    for (int kc = 0; kc < 8; ++kc){
      wr[s][kc] = *(const f16x8*)(Whh + (size_t)(wave*64 + s*16 + l16)*H_ + kc*32 + quad*8);
      asm volatile("" : "+v"(wr[s][kc]));
    }

  bnlds[tid] = bhh[512 + tid];

  // h state: lane owns (batch=l16, hidden j=jj+s*16+r), s in 0..3
  f32x4 h[4];
#pragma unroll
  for (int s = 0; s < 4; ++s){
    h[s] = *(const f32x4*)(hstate + (size_t)(b0 + l16)*H_ + jj + s*16);
    f16x4 hh;
#pragma unroll
    for (int r = 0; r < 4; ++r) hh[r] = (f16)h[s][r];
    const int ch = wave*8 + s*2 + (quad>>1);                // 16B chunk index
    *(f16x4*)&hbufB[0][l16*512 + ((ch ^ (l16&7))<<4) + ((quad&1)<<3)] = hh;
  }

  // per-lane xg / out0 bases: row = b0+l16, cols jj + {g*256, s*16}
  const f16* xgl = xg + (size_t)(b0 + l16)*G_ + jj;
  f16* o0l = out0 ? out0 + (size_t)(b0 + l16)*H_ + jj : (f16*)nullptr;
  f16x4 cur[12];   // [s*3+g]
#pragma unroll
  for (int s = 0; s < 4; ++s)
#pragma unroll
    for (int g = 0; g < 3; ++g)
      cur[s*3+g] = *(const f16x4*)(xgl + g*256 + s*16);

  __syncthreads();   // one-time full drain: hbuf[0], bnlds, weights ready

#pragma unroll 1
  for (int t = 0; t < TC; ++t){
    const int pb = t & 1;
    f32x4 accR[4] = {}, accZ[4] = {}, accN[4] = {};
#pragma unroll
    for (int kc = 0; kc < 8; ++kc){
      // B-frag: h[batch=l16][k=kc*32+quad*8], swizzled chunk = kc*4+quad
      f16x8 hf = *(const f16x8*)&hbufB[pb][l16*512 + ((((kc<<2)|quad) ^ (l16&7))<<4)];
#pragma unroll
      for (int s = 0; s < 4; ++s){
        accR[s] = __builtin_amdgcn_mfma_f32_16x16x32_f16(wr[s][kc], hf, accR[s], 0,0,0);
        accZ[s] = __builtin_amdgcn_mfma_f32_16x16x32_f16(wz[s][kc], hf, accZ[s], 0,0,0);
        accN[s] = __builtin_amdgcn_mfma_f32_16x16x32_f16(wn[s][kc], hf, accN[s], 0,0,0);
      }
    }
#pragma unroll
    for (int s = 0; s < 4; ++s){
      const f32x4 bnv = *(const f32x4*)&bnlds[jj + s*16];
      f16x4 hh;
#pragma unroll
      for (int r = 0; r < 4; ++r){
        float rg = sigm((float)cur[s*3+0][r] + accR[s][r]);
        float zg = sigm((float)cur[s*3+1][r] + accZ[s][r]);
        float ng = tanh_((float)cur[s*3+2][r] + rg*(accN[s][r] + bnv[r]));
        float hv = ng + zg*(h[s][r] - ng);
        h[s][r] = hv;
        hh[r]   = (f16)hv;
      }
      const int ch = wave*8 + s*2 + (quad>>1);
      *(f16x4*)&hbufB[pb^1][l16*512 + ((ch ^ (l16&7))<<4) + ((quad&1)<<3)] = hh;
      if (o0l)
        *(f16x4*)(o0l + (size_t)t*(B_*H_) + s*16) = hh;
    }
    if (t+1 < TC){  // xg(t+1) into cur; stays in flight across the barrier
      const f16* xn_ = xgl + (size_t)(t+1)*(B_*G_);
#pragma unroll
      for (int s = 0; s < 4; ++s)
#pragma unroll
        for (int g = 0; g < 3; ++g)
          cur[s*3+g] = *(const f16x4*)(xn_ + g*256 + s*16);
    }
    bar_lds();   // h(t) visible in hbuf[pb^1]; VMEM ops NOT drained
  }

#pragma unroll
  for (int s = 0; s < 4; ++s)
    *(f32x4*)(hstate + (size_t)(b0 + l16)*H_ + jj + s*16) = h[s];
}

// --------------------------------------------------------------------------
// fused: [scan L0] || [scan L1] || [gemm0 next chunk] || [gemm1 prev chunk]
// 256-thread blocks: [0,16) L0, [16,32) L1, [32,32+2TC) gemm0,
// [32+2TC,32+4TC) gemm1.  mask: bit0 L0, bit1 L1, bit2 g0, bit3 g1.
// grid = 32+4TC (=160 at TC=32) <= 256 CUs, 1 block/CU.
// --------------------------------------------------------------------------
__global__ __launch_bounds__(256, 1)
__attribute__((amdgpu_waves_per_eu(1, 1)))
void fused(
    const f16* __restrict__ xg0, const f16* __restrict__ Whh0,
    const float* __restrict__ bhh0, float* __restrict__ h0s,
    f16* __restrict__ out0w,
    const f16* __restrict__ xg1, const f16* __restrict__ Whh1,
    const float* __restrict__ bhh1, float* __restrict__ h1s,
    const f16* __restrict__ g0A, const f16* __restrict__ g0W,
    const float* __restrict__ g0b, f16* __restrict__ g0out,
    const f16* __restrict__ g1A, const f16* __restrict__ g1W,
    const float* __restrict__ g1b, f16* __restrict__ g1out,
    const int TC, const int mask){
  const int bid = blockIdx.x;
  if (bid < 16){
    if (!(mask & 1)) return;
    scan_body(xg0, Whh0, bhh0, h0s, out0w, TC, bid);
  } else if (bid < 32){
    if (!(mask & 2)) return;
    scan_body(xg1, Whh1, bhh1, h1s, (f16*)nullptr, TC, bid - 16);
  } else {
    int g = bid - 32;
    if (g < 2*TC){
      if (!(mask & 4)) return;
      gemm_body4<96>(g0A, g0W, g0b, g0out, g % TC, g / TC);
    } else {
      g -= 2*TC;
      if (!(mask & 8)) return;
      gemm_body4<256>(g1A, g1W, g1b, g1out, g % TC, g / TC);
    }
  }
}

// --------------------------------------------------------------------------
extern "C" void kernel_launch(void* const* d_in, const int* in_sizes, int n_in,
                              void* d_out, int out_size, void* d_ws, size_t ws_size,
                              hipStream_t stream){
  (void)in_sizes; (void)n_in; (void)out_size;
  const float* x    = (const float*)d_in[0];
  const float* Wih0 = (const float*)d_in[1];
  const float* Whh0 = (const float*)d_in[2];
  const float* bih0 = (const float*)d_in[3];
  const float* bhh0 = (const float*)d_in[4];
  const float* Wih1 = (const float*)d_in[5];
  const float* Whh1 = (const float*)d_in[6];
  const float* bih1 = (const float*)d_in[7];
  const float* bhh1 = (const float*)d_in[8];
  const float* fcW  = (const float*)d_in[9];
  const float* fcb  = (const float*)d_in[10];

  char* ws = (char*)d_ws;
  size_t off = 0;
  auto alloc = [&](size_t bytes) -> void* {
    void* p = ws + off; off += (bytes + 255) & ~(size_t)255; return p;
  };
  f16*   xb    = (f16*)  alloc((size_t)MROWS*KX*2);   // 25.2 MB
  f16*   W0h   = (f16*)  alloc((size_t)G_*KX*2);
  f16*   Whh0h = (f16*)  alloc((size_t)G_*H_*2);
  f16*   Wih1h = (f16*)  alloc((size_t)G_*H_*2);
  f16*   Whh1h = (f16*)  alloc((size_t)G_*H_*2);
  f16*   fcWh  = (f16*)  alloc((size_t)H_*H_*2);
  float* bias0 = (float*)alloc(G_*4);
  float* bias1 = (float*)alloc(G_*4);
  float* h0s   = (float*)alloc((size_t)B_*H_*4);      // h-state, both layers
  float* h1s   = (float*)alloc((size_t)B_*H_*4);      //   (adjacent: one memset)
  f16*   hTh   = (f16*)  alloc((size_t)B_*H_*2);
  const size_t fixed = off;

  // TC=32: double-buffered xg (both layers) + out0. Per-TC bytes:
  // 4*B*G*2 + 2*B*H*2 = 1,835,008. Fallback shrink if ws is tight.
  int TC = 32;
  while (TC > 8 && fixed + (size_t)TC*1835008 + 1024 > ws_size) TC >>= 1;
  f16* xg0[2], *xg1[2], *out0[2];
  xg0[0]  = (f16*)alloc((size_t)TC*B_*G_*2);
  xg0[1]  = (f16*)alloc((size_t)TC*B_*G_*2);
  xg1[0]  = (f16*)alloc((size_t)TC*B_*G_*2);
  xg1[1]  = (f16*)alloc((size_t)TC*B_*G_*2);
  out0[0] = (f16*)alloc((size_t)TC*B_*H_*2);
  out0[1] = (f16*)alloc((size_t)TC*B_*H_*2);
  const int nc = T_ / TC;

  hipMemsetAsync(h0s, 0, (size_t)B_*H_*4*2, stream);  // zero h0s+h1s (adjacent)
  hipLaunchKernelGGL(cast_x, dim3(49152), dim3(256), 0, stream, x, xb);
  hipLaunchKernelGGL(cast_w, dim3(2854), dim3(256), 0, stream,
                     Wih0, Whh0, Wih1, Whh1, fcW, bih0, bhh0, bih1, bhh1,
                     W0h, Whh0h, Wih1h, Whh1h, fcWh, bias0, bias1);

  // prologue: xg0[0] = xb[chunk 0] @ W_ih0^T + bias0
  hipLaunchKernelGGL((gemm_k<96,192,false>), dim3(TC*2,4), dim3(256), 0, stream,
                     xb, W0h, bias0, (void*)xg0[0], G_);

  const dim3 grid(32 + 4*TC);
  for (int i = 0; i <= nc + 1; ++i){
    int mask = 0;
    if (i < nc)            mask |= 1;   // L0 scans chunk i
    if (i >= 2)            mask |= 2;   // L1 scans chunk i-2
    if (i + 1 < nc)        mask |= 4;   // gemm0 builds chunk i+1
    if (i >= 1 && i <= nc) mask |= 8;   // gemm1 builds chunk i-1
    hipLaunchKernelGGL(fused, grid, dim3(256), 0, stream,
                       xg0[i&1], Whh0h, bhh0, h0s, out0[i&1],
                       xg1[i&1], Whh1h, bhh1, h1s,
                       xb + (size_t)(i+1)*TC*B_*KX, W0h, bias0, xg0[(i+1)&1],
                       out0[(i+1)&1], Wih1h, bias1, xg1[(i+1)&1],
                       TC, mask);
  }

  // embedding = hT @ fc_W^T + fc_b (f32 out)
  hipLaunchKernelGGL(cast_h, dim3(256), dim3(256), 0, stream, h1s, hTh);
  hipLaunchKernelGGL((gemm_k<256,64,true>), dim3(2,4), dim3(256), 0, stream,
                     hTh, fcWh, fcb, d_out, H_);
}

// Round 10
// 2646.241 us; speedup vs baseline: 1.0643x; 1.0643x over previous
//
#include <hip/hip_runtime.h>
#include <hip/hip_bf16.h>
#include <hip/hip_cooperative_groups.h>
#include <stdint.h>
#include <stddef.h>

namespace cg = cooperative_groups;

// ---------------------------------------------------------------------------
// GRUEncoder: x[256,512,25,3] f32 -> 2-layer GRU(H=256) -> fc(hT) -> [256,256] f32
//
// r10: persistent cooperative pipeline. One launch runs all chunks:
//   for i in 0..nc+1:  [scan L0 chunk i] || [scan L1 chunk i-2]
//                      || [gemm0 chunk i+1] || [gemm1 chunk i-1] ; grid.sync()
// Scan WGs load W_hh (r,z -> 128 AGPR; n -> 128KB LDS) ONCE and keep h in
// registers across all 512 steps -- deletes the per-launch weight reload
// (~8-15us x 17) and h-state round trips. Step body byte-identical to r8
// (best verified: 1688us total, 90.7us/chunk-dispatch).
// Fallback: if cooperative launch is rejected, run the r8 multi-launch path.
// ---------------------------------------------------------------------------

typedef _Float16 f16;
typedef _Float16 f16x8 __attribute__((ext_vector_type(8)));
typedef _Float16 f16x4 __attribute__((ext_vector_type(4)));
typedef float    f32x4 __attribute__((ext_vector_type(4)));

#define B_      256
#define T_      512
#define H_      256
#define G_      768      // 3*H
#define IN_RAW  75
#define KX      96       // padded input K
#define MROWS   (T_*B_)  // 131072

__device__ __forceinline__ float rcp_(float x){ return __builtin_amdgcn_rcpf(x); }
__device__ __forceinline__ float sigm(float x){ return rcp_(1.f + __expf(-x)); }
__device__ __forceinline__ float tanh_(float x){ return 1.f - 2.f*rcp_(1.f + __expf(2.f*x)); }

// barrier that waits ONLY on LDS ops (no vmcnt/expcnt drain).
__device__ __forceinline__ void bar_lds(){
  asm volatile("s_waitcnt lgkmcnt(0)" ::: "memory");
  __builtin_amdgcn_s_barrier();
  __builtin_amdgcn_sched_barrier(0);   // no hoisting of LDS reads above barrier
}

// --------------------------------------------------------------------------
// cast_x: x[b][t][j] (f32) -> xb[t*256+b][96] (fp16, j>=75 zero)
// --------------------------------------------------------------------------
__global__ __launch_bounds__(256) void cast_x(const float* __restrict__ x,
                                              f16* __restrict__ xb){
  int idx = blockIdx.x*256 + threadIdx.x;        // grid*256 == 131072*96 exact
  int row = idx / KX;
  int j   = idx - row*KX;
  int t   = row >> 8;        // row = t*256 + b
  int b   = row & 255;
  float v = (j < IN_RAW) ? x[((size_t)b*T_ + t)*IN_RAW + j] : 0.f;
  xb[idx] = (f16)v;
}

// --------------------------------------------------------------------------
// cast_w: all weight casts + fused biases. grid*256 == 730624 exact.
// --------------------------------------------------------------------------
__global__ __launch_bounds__(256) void cast_w(
    const float* __restrict__ Wih0, const float* __restrict__ Whh0,
    const float* __restrict__ Wih1, const float* __restrict__ Whh1,
    const float* __restrict__ fcW,
    const float* __restrict__ bih0, const float* __restrict__ bhh0,
    const float* __restrict__ bih1, const float* __restrict__ bhh1,
    f16* __restrict__ W0h, f16* __restrict__ Whh0h, f16* __restrict__ Wih1h,
    f16* __restrict__ Whh1h, f16* __restrict__ fcWh,
    float* __restrict__ bias0, float* __restrict__ bias1){
  int i = blockIdx.x*256 + threadIdx.x;
  if (i < 73728){ int r = i/KX, j = i - r*KX;
    W0h[i] = (f16)((j < IN_RAW) ? Wih0[r*IN_RAW + j] : 0.f); return; }
  i -= 73728;
  if (i < 196608){ Whh0h[i] = (f16)Whh0[i]; return; } i -= 196608;
  if (i < 196608){ Wih1h[i] = (f16)Wih1[i]; return; } i -= 196608;
  if (i < 196608){ Whh1h[i] = (f16)Whh1[i]; return; } i -= 196608;
  if (i < 65536){ fcWh[i] = (f16)fcW[i]; return; } i -= 65536;
  if (i < 768){ bias0[i] = bih0[i] + (i < 512 ? bhh0[i] : 0.f); return; } i -= 768;
  if (i < 768){ bias1[i] = bih1[i] + (i < 512 ? bhh1[i] : 0.f); }
}

// --------------------------------------------------------------------------
// cast_h: h1s f32 [256*256] -> hT fp16
// --------------------------------------------------------------------------
__global__ __launch_bounds__(256) void cast_h(const float* __restrict__ hs,
                                              f16* __restrict__ hT){
  int i = blockIdx.x*256 + threadIdx.x;
  hT[i] = (f16)hs[i];
}

// --------------------------------------------------------------------------
// gemm_k: out[M,N] = A[M,K](fp16) @ W[N,K]^T(fp16) + bias. 256-thread/8-wave
// standalone kernel for the prologue gemm and the fc epilogue.
// --------------------------------------------------------------------------
template<int K, int BN, bool OUTF32>
__global__ __launch_bounds__(256, 2) void gemm_k(const f16* __restrict__ A,
    const f16* __restrict__ W, const float* __restrict__ bias,
    void* __restrict__ outp, const int N){
  constexpr int NT = BN/16;
  const int tid  = threadIdx.x;
  const int wave = tid >> 6, lane = tid & 63;
  const int quad = lane >> 4, l16 = lane & 15;
  const long mbase = (long)blockIdx.x*128 + wave*32;
  const int  nbase = blockIdx.y*BN;
  f32x4 acc[2][NT] = {};
#pragma unroll 2
  for (int kc = 0; kc < K/32; ++kc){
    f16x8 a0 = *(const f16x8*)(A + (mbase +      l16)*K + kc*32 + quad*8);
    f16x8 a1 = *(const f16x8*)(A + (mbase + 16 + l16)*K + kc*32 + quad*8);
#pragma unroll
    for (int nt = 0; nt < NT; ++nt){
      f16x8 b = *(const f16x8*)(W + (long)(nbase + nt*16 + l16)*K + kc*32 + quad*8);
      acc[0][nt] = __builtin_amdgcn_mfma_f32_16x16x32_f16(a0, b, acc[0][nt], 0, 0, 0);
      acc[1][nt] = __builtin_amdgcn_mfma_f32_16x16x32_f16(a1, b, acc[1][nt], 0, 0, 0);
    }
  }
#pragma unroll
  for (int nt = 0; nt < NT; ++nt){
    const int col = nbase + nt*16 + l16;
    const float bv = bias[col];
#pragma unroll
    for (int af = 0; af < 2; ++af){
#pragma unroll
      for (int r = 0; r < 4; ++r){
        const long row = mbase + af*16 + quad*4 + r;   // D row = quad*4 + reg
        float v = acc[af][nt][r] + bv;
        if (OUTF32) ((float*)outp)[row*(long)N + col] = v;
        else        ((f16*)outp)[row*(long)N + col] = (f16)v;
      }
    }
  }
}

// --------------------------------------------------------------------------
// gemm_body128: 512-thread (8-wave) GEMM tile. Block covers 512 rows
// (2 sequential 256-row tiles) x 128 cols, N=768. acc = 64 regs.
// --------------------------------------------------------------------------
template<int K>
__device__ __forceinline__ void gemm_body128(const f16* __restrict__ A,
    const f16* __restrict__ W, const float* __restrict__ bias,
    f16* __restrict__ out, const int bx, const int by){
  const int tid  = threadIdx.x;
  const int wave = tid >> 6, lane = tid & 63;
  const int quad = lane >> 4, l16 = lane & 15;
  const int nbase = by*128;
#pragma unroll
  for (int mt = 0; mt < 2; ++mt){
    const long mbase = (long)bx*512 + mt*256 + wave*32;
    f32x4 acc[2][8] = {};
#pragma unroll 2
    for (int kc = 0; kc < K/32; ++kc){
      f16x8 a0 = *(const f16x8*)(A + (mbase +      l16)*K + kc*32 + quad*8);
      f16x8 a1 = *(const f16x8*)(A + (mbase + 16 + l16)*K + kc*32 + quad*8);
#pragma unroll
      for (int nt = 0; nt < 8; ++nt){
        f16x8 b = *(const f16x8*)(W + (long)(nbase + nt*16 + l16)*K + kc*32 + quad*8);
        acc[0][nt] = __builtin_amdgcn_mfma_f32_16x16x32_f16(a0, b, acc[0][nt], 0, 0, 0);
        acc[1][nt] = __builtin_amdgcn_mfma_f32_16x16x32_f16(a1, b, acc[1][nt], 0, 0, 0);
      }
    }
#pragma unroll
    for (int nt = 0; nt < 8; ++nt){
      const int col = nbase + nt*16 + l16;
      const float bv = bias[col];
#pragma unroll
      for (int af = 0; af < 2; ++af)
#pragma unroll
        for (int r = 0; r < 4; ++r)
          out[(mbase + af*16 + quad*4 + r)*(long)G_ + col] = (f16)(acc[af][nt][r] + bv);
    }
  }
}

// --------------------------------------------------------------------------
// scan_body (fallback path): identical to r8.
// --------------------------------------------------------------------------
__device__ __forceinline__ void scan_body(const f16* __restrict__ xg,
    const f16* __restrict__ Whh, const float* __restrict__ bhh,
    float* __restrict__ hstate, f16* __restrict__ out0,
    const int TC, const int bx){
  __shared__ char  hbufB[2][8192];     // 16 KB: h(t) fp16, XOR-swizzled
  __shared__ f16   nlds[65536];        // 128 KB: full n-gate, A-frag order
  __shared__ float bnlds[256];         // n-gate hidden bias
  const int tid  = threadIdx.x;
  const int wave = tid >> 6, lane = tid & 63;
  const int quad = lane >> 4, l16 = lane & 15;
  const int b0   = bx*16;
  const int jj   = wave*32 + quad*4;

  f16x8 w[2][2][8];
#pragma unroll
  for (int s = 0; s < 2; ++s)
#pragma unroll
    for (int g = 0; g < 2; ++g)
#pragma unroll
      for (int kc = 0; kc < 8; ++kc)
        w[s][g][kc] = *(const f16x8*)(Whh + (size_t)(g*256 + wave*32 + s*16 + l16)*H_ + kc*32 + quad*8);
#pragma unroll
  for (int s = 0; s < 2; ++s)
#pragma unroll
    for (int g = 0; g < 2; ++g)
#pragma unroll
      for (int kc = 0; kc < 8; ++kc)
        asm volatile("" : "+a"(w[s][g][kc]));

#pragma unroll
  for (int i = 0; i < 16; ++i){
    const int p  = i*512 + tid;
    const int f  = p >> 6, L = p & 63;
    const int wv = f >> 4, ss = (f >> 3) & 1, kcc = f & 7;
    const int row = 512 + wv*32 + ss*16 + (L & 15);
    const int k   = kcc*32 + (L >> 4)*8;
    *(f16x8*)&nlds[(size_t)p*8] = *(const f16x8*)(Whh + (size_t)row*H_ + k);
  }
  if (tid < 256) bnlds[tid] = bhh[512 + tid];

  f32x4 h[2];
#pragma unroll
  for (int s = 0; s < 2; ++s){
    h[s] = *(const f32x4*)(hstate + (size_t)(b0 + l16)*H_ + jj + s*16);
    f16x4 hh;
#pragma unroll
    for (int r = 0; r < 4; ++r) hh[r] = (f16)h[s][r];
    const int ch = wave*4 + s*2 + (quad>>1);
    *(f16x4*)&hbufB[0][l16*512 + ((ch ^ (l16&7))<<4) + ((quad&1)<<3)] = hh;
  }

  const f16* xgl = xg + (size_t)(b0 + l16)*G_ + jj;
  f16x4 cur[6];
#pragma unroll
  for (int s = 0; s < 2; ++s)
#pragma unroll
    for (int g = 0; g < 3; ++g)
      cur[s*3+g] = *(const f16x4*)(xgl + g*256 + s*16);

  __syncthreads();

  for (int t = 0; t < TC; ++t){
    const int pb = t & 1;
    f32x4 acc[2][3] = {};
#pragma unroll
    for (int kc = 0; kc < 8; ++kc){
      f16x8 hf = *(const f16x8*)&hbufB[pb][l16*512 + ((((kc<<2)|quad) ^ (l16&7))<<4)];
#pragma unroll
      for (int s = 0; s < 2; ++s){
        acc[s][0] = __builtin_amdgcn_mfma_f32_16x16x32_f16(w[s][0][kc], hf, acc[s][0], 0,0,0);
        acc[s][1] = __builtin_amdgcn_mfma_f32_16x16x32_f16(w[s][1][kc], hf, acc[s][1], 0,0,0);
        f16x8 nf = *(const f16x8*)&nlds[(size_t)(((wave<<4)|(s<<3)|kc)*64 + lane)*8];
        acc[s][2] = __builtin_amdgcn_mfma_f32_16x16x32_f16(nf, hf, acc[s][2], 0,0,0);
      }
    }
    f16x4 hh[2];
#pragma unroll
    for (int s = 0; s < 2; ++s){
      const f32x4 bnv = *(const f32x4*)&bnlds[jj + s*16];
#pragma unroll
      for (int r = 0; r < 4; ++r){
        float rg = sigm((float)cur[s*3+0][r] + acc[s][0][r]);
        float zg = sigm((float)cur[s*3+1][r] + acc[s][1][r]);
        float ng = tanh_((float)cur[s*3+2][r] + rg*(acc[s][2][r] + bnv[r]));
        float hv = (1.f - zg)*ng + zg*h[s][r];
        h[s][r] = hv;
        hh[s][r] = (f16)hv;
      }
    }
    if (t+1 < TC){
      const f16* xn_ = xgl + (size_t)(t+1)*(B_*G_);
#pragma unroll
      for (int s = 0; s < 2; ++s)
#pragma unroll
        for (int g = 0; g < 3; ++g)
          cur[s*3+g] = *(const f16x4*)(xn_ + g*256 + s*16);
    }
#pragma unroll
    for (int s = 0; s < 2; ++s){
      const int ch = wave*4 + s*2 + (quad>>1);
      *(f16x4*)&hbufB[pb^1][l16*512 + ((ch ^ (l16&7))<<4) + ((quad&1)<<3)] = hh[s];
      if (out0)
        *(f16x4*)(out0 + ((size_t)t*B_ + b0 + l16)*H_ + jj + s*16) = hh[s];
    }
    bar_lds();
  }

#pragma unroll
  for (int s = 0; s < 2; ++s)
    *(f32x4*)(hstate + (size_t)(b0 + l16)*H_ + jj + s*16) = h[s];
}

// --------------------------------------------------------------------------
// fused (fallback, r8): one chunk per launch.
// --------------------------------------------------------------------------
__global__ __launch_bounds__(512)
__attribute__((amdgpu_waves_per_eu(2, 2)))
void fused(
    const f16* __restrict__ xg0, const f16* __restrict__ Whh0,
    const float* __restrict__ bhh0, float* __restrict__ h0s,
    f16* __restrict__ out0w,
    const f16* __restrict__ xg1, const f16* __restrict__ Whh1,
    const float* __restrict__ bhh1, float* __restrict__ h1s,
    const f16* __restrict__ g0A, const f16* __restrict__ g0W,
    const float* __restrict__ g0b, f16* __restrict__ g0out,
    const f16* __restrict__ g1A, const f16* __restrict__ g1W,
    const float* __restrict__ g1b, f16* __restrict__ g1out,
    const int TC, const int mask){
  const int bid = blockIdx.x;
  if (bid < 16){
    if (!(mask & 1)) return;
    scan_body(xg0, Whh0, bhh0, h0s, out0w, TC, bid);
  } else if (bid < 32){
    if (!(mask & 2)) return;
    scan_body(xg1, Whh1, bhh1, h1s, (f16*)nullptr, TC, bid - 16);
  } else {
    int g = bid - 32;
    const int RB = TC/2;
    if (g < 3*TC){
      if (!(mask & 4)) return;
      gemm_body128<96>(g0A, g0W, g0b, g0out, g % RB, g / RB);
    } else {
      g -= 3*TC;
      if (!(mask & 8)) return;
      gemm_body128<256>(g1A, g1W, g1b, g1out, g % RB, g / RB);
    }
  }
}

// --------------------------------------------------------------------------
// fusedP: persistent cooperative pipeline. grid = 32 + 6*TC blocks x 512 thr.
// Scan blocks [0,32): load weights ONCE, h in regs across all chunks, run
// chunk per iteration. Gemm blocks [32,..): tile per iteration.
// grid.sync() between iterations; double-buffered xg/out0 by parity.
// --------------------------------------------------------------------------
__global__ __launch_bounds__(512)
__attribute__((amdgpu_waves_per_eu(2, 2)))
void fusedP(const f16* __restrict__ xb,
            const f16* __restrict__ W0h, const float* __restrict__ bias0,
            const f16* __restrict__ Whh0h, const float* __restrict__ bhh0,
            const f16* __restrict__ Wih1h, const float* __restrict__ bias1,
            const f16* __restrict__ Whh1h, const float* __restrict__ bhh1,
            float* __restrict__ h1s,
            f16* __restrict__ xg0a, f16* __restrict__ xg0b,
            f16* __restrict__ xg1a, f16* __restrict__ xg1b,
            f16* __restrict__ out0a, f16* __restrict__ out0b,
            const int TC, const int nc){
  cg::grid_group gg = cg::this_grid();
  const int bid = blockIdx.x;
  if (bid < 32){
    __shared__ char  hbufB[2][8192];   // h(t) fp16, XOR-swizzled
    __shared__ f16   nlds[65536];      // full n-gate, A-frag order
    __shared__ float bnlds[256];
    const bool L1w = bid >= 16;
    const f16*   Whh = L1w ? Whh1h : Whh0h;
    const float* bhh = L1w ? bhh1  : bhh0;
    const int tid  = threadIdx.x;
    const int wave = tid >> 6, lane = tid & 63;
    const int quad = lane >> 4, l16 = lane & 15;
    const int b0   = (bid & 15)*16;
    const int jj   = wave*32 + quad*4;

    // r,z weights -> AGPR (once)
    f16x8 w[2][2][8];
#pragma unroll
    for (int s = 0; s < 2; ++s)
#pragma unroll
      for (int g = 0; g < 2; ++g)
#pragma unroll
        for (int kc = 0; kc < 8; ++kc)
          w[s][g][kc] = *(const f16x8*)(Whh + (size_t)(g*256 + wave*32 + s*16 + l16)*H_ + kc*32 + quad*8);
#pragma unroll
    for (int s = 0; s < 2; ++s)
#pragma unroll
      for (int g = 0; g < 2; ++g)
#pragma unroll
        for (int kc = 0; kc < 8; ++kc)
          asm volatile("" : "+a"(w[s][g][kc]));

    // n weights -> LDS (once)
#pragma unroll
    for (int i = 0; i < 16; ++i){
      const int p  = i*512 + tid;
      const int f  = p >> 6, L = p & 63;
      const int wv = f >> 4, ss = (f >> 3) & 1, kcc = f & 7;
      const int row = 512 + wv*32 + ss*16 + (L & 15);
      const int k   = kcc*32 + (L >> 4)*8;
      *(f16x8*)&nlds[(size_t)p*8] = *(const f16x8*)(Whh + (size_t)row*H_ + k);
    }
    if (tid < 256) bnlds[tid] = bhh[512 + tid];

    // h = 0, staged into hbuf[0]; parity is continuous across chunks (TC even)
    f32x4 h[2] = {};
#pragma unroll
    for (int s = 0; s < 2; ++s){
      const int ch = wave*4 + s*2 + (quad>>1);
      *(f16x4*)&hbufB[0][l16*512 + ((ch ^ (l16&7))<<4) + ((quad&1)<<3)] = (f16x4){0,0,0,0};
    }
    __syncthreads();

    for (int i = 0; i <= nc + 1; ++i){
      const int c = L1w ? i - 2 : i;
      if (c >= 0 && c < nc){
        const f16* xgc = L1w ? ((c&1) ? xg1b : xg1a) : ((c&1) ? xg0b : xg0a);
        f16* o0c       = L1w ? (f16*)nullptr        : ((c&1) ? out0b : out0a);
        const f16* xgl = xgc + (size_t)(b0 + l16)*G_ + jj;
        f16* o0l = o0c ? o0c + (size_t)(b0 + l16)*H_ + jj : (f16*)nullptr;
        f16x4 cur[6];
#pragma unroll
        for (int s = 0; s < 2; ++s)
#pragma unroll
          for (int g = 0; g < 3; ++g)
            cur[s*3+g] = *(const f16x4*)(xgl + g*256 + s*16);

        for (int t = 0; t < TC; ++t){
          const int pb = t & 1;
          f32x4 acc[2][3] = {};
#pragma unroll
          for (int kc = 0; kc < 8; ++kc){
            f16x8 hf = *(const f16x8*)&hbufB[pb][l16*512 + ((((kc<<2)|quad) ^ (l16&7))<<4)];
#pragma unroll
            for (int s = 0; s < 2; ++s){
              acc[s][0] = __builtin_amdgcn_mfma_f32_16x16x32_f16(w[s][0][kc], hf, acc[s][0], 0,0,0);
              acc[s][1] = __builtin_amdgcn_mfma_f32_16x16x32_f16(w[s][1][kc], hf, acc[s][1], 0,0,0);
              f16x8 nf = *(const f16x8*)&nlds[(size_t)(((wave<<4)|(s<<3)|kc)*64 + lane)*8];
              acc[s][2] = __builtin_amdgcn_mfma_f32_16x16x32_f16(nf, hf, acc[s][2], 0,0,0);
            }
          }
          f16x4 hh[2];
#pragma unroll
          for (int s = 0; s < 2; ++s){
            const f32x4 bnv = *(const f32x4*)&bnlds[jj + s*16];
#pragma unroll
            for (int r = 0; r < 4; ++r){
              float rg = sigm((float)cur[s*3+0][r] + acc[s][0][r]);
              float zg = sigm((float)cur[s*3+1][r] + acc[s][1][r]);
              float ng = tanh_((float)cur[s*3+2][r] + rg*(acc[s][2][r] + bnv[r]));
              float hv = (1.f - zg)*ng + zg*h[s][r];
              h[s][r] = hv;
              hh[s][r] = (f16)hv;
            }
          }
          if (t+1 < TC){
            const f16* xn_ = xgl + (size_t)(t+1)*(B_*G_);
#pragma unroll
            for (int s = 0; s < 2; ++s)
#pragma unroll
              for (int g = 0; g < 3; ++g)
                cur[s*3+g] = *(const f16x4*)(xn_ + g*256 + s*16);
          }
#pragma unroll
          for (int s = 0; s < 2; ++s){
            const int ch = wave*4 + s*2 + (quad>>1);
            *(f16x4*)&hbufB[pb^1][l16*512 + ((ch ^ (l16&7))<<4) + ((quad&1)<<3)] = hh[s];
            if (o0l)
              *(f16x4*)(o0l + (size_t)t*(B_*H_) + s*16) = hh[s];
          }
          bar_lds();
        }
      }
      __threadfence();
      gg.sync();
    }
    if (L1w){
#pragma unroll
      for (int s = 0; s < 2; ++s)
        *(f32x4*)(h1s + (size_t)(b0 + l16)*H_ + jj + s*16) = h[s];
    }
  } else {
    const int g0 = bid - 32;
    const int RB = TC/2;
    for (int i = 0; i <= nc + 1; ++i){
      if (g0 < 3*TC){
        if (i + 1 < nc)
          gemm_body128<96>(xb + (size_t)(i+1)*TC*B_*KX, W0h, bias0,
                           ((i+1)&1) ? xg0b : xg0a, g0 % RB, g0 / RB);
      } else {
        const int g1 = g0 - 3*TC;
        if (i >= 1 && i <= nc)
          gemm_body128<256>(((i+1)&1) ? out0b : out0a, Wih1h, bias1,
                            ((i+1)&1) ? xg1b : xg1a, g1 % RB, g1 / RB);
      }
      __threadfence();
      gg.sync();
    }
  }
}

// --------------------------------------------------------------------------
extern "C" void kernel_launch(void* const* d_in, const int* in_sizes, int n_in,
                              void* d_out, int out_size, void* d_ws, size_t ws_size,
                              hipStream_t stream){
  (void)in_sizes; (void)n_in; (void)out_size;
  const float* x    = (const float*)d_in[0];
  const float* Wih0 = (const float*)d_in[1];
  const float* Whh0 = (const float*)d_in[2];
  const float* bih0 = (const float*)d_in[3];
  const float* bhh0 = (const float*)d_in[4];
  const float* Wih1 = (const float*)d_in[5];
  const float* Whh1 = (const float*)d_in[6];
  const float* bih1 = (const float*)d_in[7];
  const float* bhh1 = (const float*)d_in[8];
  const float* fcW  = (const float*)d_in[9];
  const float* fcb  = (const float*)d_in[10];

  char* ws = (char*)d_ws;
  size_t off = 0;
  auto alloc = [&](size_t bytes) -> void* {
    void* p = ws + off; off += (bytes + 255) & ~(size_t)255; return p;
  };
  f16*   xb    = (f16*)  alloc((size_t)MROWS*KX*2);   // 25.2 MB
  f16*   W0h   = (f16*)  alloc((size_t)G_*KX*2);
  f16*   Whh0h = (f16*)  alloc((size_t)G_*H_*2);
  f16*   Wih1h = (f16*)  alloc((size_t)G_*H_*2);
  f16*   Whh1h = (f16*)  alloc((size_t)G_*H_*2);
  f16*   fcWh  = (f16*)  alloc((size_t)H_*H_*2);
  float* bias0 = (float*)alloc(G_*4);
  float* bias1 = (float*)alloc(G_*4);
  float* h0s   = (float*)alloc((size_t)B_*H_*4);      // h-state (fallback)
  float* h1s   = (float*)alloc((size_t)B_*H_*4);
  f16*   hTh   = (f16*)  alloc((size_t)B_*H_*2);
  const size_t fixed = off;

  int TC = 32;
  while (TC > 8 && fixed + (size_t)TC*1835008 + 1024 > ws_size) TC >>= 1;
  f16* xg0[2], *xg1[2], *out0[2];
  xg0[0]  = (f16*)alloc((size_t)TC*B_*G_*2);
  xg0[1]  = (f16*)alloc((size_t)TC*B_*G_*2);
  xg1[0]  = (f16*)alloc((size_t)TC*B_*G_*2);
  xg1[1]  = (f16*)alloc((size_t)TC*B_*G_*2);
  out0[0] = (f16*)alloc((size_t)TC*B_*H_*2);
  out0[1] = (f16*)alloc((size_t)TC*B_*H_*2);
  const int nc = T_ / TC;

  hipMemsetAsync(h0s, 0, (size_t)B_*H_*4*2, stream);  // needed iff fallback
  hipLaunchKernelGGL(cast_x, dim3(49152), dim3(256), 0, stream, x, xb);
  hipLaunchKernelGGL(cast_w, dim3(2854), dim3(256), 0, stream,
                     Wih0, Whh0, Wih1, Whh1, fcW, bih0, bhh0, bih1, bhh1,
                     W0h, Whh0h, Wih1h, Whh1h, fcWh, bias0, bias1);

  // prologue: xg0[0] = xb[chunk 0] @ W_ih0^T + bias0 (both paths)
  hipLaunchKernelGGL((gemm_k<96,192,false>), dim3(TC*2,4), dim3(256), 0, stream,
                     xb, W0h, bias0, (void*)xg0[0], G_);

  // persistent cooperative pipeline
  {
    const f16* xb_ = xb; const f16* W0h_ = W0h; const float* b0_ = bias0;
    const f16* Wh0_ = Whh0h; const float* bh0_ = bhh0;
    const f16* Wi1_ = Wih1h; const float* b1_ = bias1;
    const f16* Wh1_ = Whh1h; const float* bh1_ = bhh1;
    float* h1s_ = h1s;
    f16 *x0a = xg0[0], *x0b = xg0[1], *x1a = xg1[0], *x1b = xg1[1];
    f16 *o0a = out0[0], *o0b = out0[1];
    int TC_ = TC, nc_ = nc;
    void* kargs[] = { &xb_, &W0h_, &b0_, &Wh0_, &bh0_, &Wi1_, &b1_, &Wh1_, &bh1_,
                      &h1s_, &x0a, &x0b, &x1a, &x1b, &o0a, &o0b, &TC_, &nc_ };
    hipError_t e = hipLaunchCooperativeKernel((void*)fusedP, dim3(32 + 6*TC),
                                              dim3(512), kargs, 0, stream);
    if (e != hipSuccess){
      // fallback: r8 multi-launch pipeline (verified 1688us)
      for (int i = 0; i <= nc + 1; ++i){
        int mask = 0;
        if (i < nc)            mask |= 1;
        if (i >= 2)            mask |= 2;
        if (i + 1 < nc)        mask |= 4;
        if (i >= 1 && i <= nc) mask |= 8;
        hipLaunchKernelGGL(fused, dim3(32 + 6*TC), dim3(512), 0, stream,
                           xg0[i&1], Whh0h, bhh0, h0s, out0[i&1],
                           xg1[i&1], Whh1h, bhh1, h1s,
                           xb + (size_t)(i+1)*TC*B_*KX, W0h, bias0, xg0[(i+1)&1],
                           out0[(i+1)&1], Wih1h, bias1, xg1[(i+1)&1],
                           TC, mask);
      }
    }
  }

  // embedding = hT @ fc_W^T + fc_b (f32 out)
  hipLaunchKernelGGL(cast_h, dim3(256), dim3(256), 0, stream, h1s, hTh);
  hipLaunchKernelGGL((gemm_k<256,64,true>), dim3(2,4), dim3(256), 0, stream,
                     hTh, fcWh, fcb, d_out, H_);
}

// Round 11
// 2204.078 us; speedup vs baseline: 1.2778x; 1.2006x over previous
//
#include <hip/hip_runtime.h>
#include <hip/hip_bf16.h>
#include <stdint.h>
#include <stddef.h>

// ---------------------------------------------------------------------------
// GRUEncoder: x[256,512,25,3] f32 -> 2-layer GRU(H=256) -> fc(hT) -> [256,256] f32
//
// Fused pipelined schedule (chunk = TC steps, 2-chunk layer skew):
//   cast_x ; cast_w ; gemm0(chunk0)
//   for i in 0..nc+1:   ONE launch: [scan L0 chunk i] || [scan L1 chunk i-2]
//                                   || [gemm0 chunk i+1] || [gemm1 chunk i-1]
//   cast_h ; fc gemm
//
// Scan, swapped MFMA operands: D[gate rows x batch cols] = Whh * h.
//   - r,z weights pinned in 128 AGPR ("a")
//   - n-gate s=0 half pinned in 32 VGPR ("v"), s=1 half streamed from 64KB LDS
//     (r11: halves the n-gate LDS stream -- the largest per-step cost;
//      208 -> 136 ds_reads/CU/step)
//   - bn bias in registers (was LDS); acc init = gate inputs / bias
//   - hbuf XOR-swizzled, double-buffered, ONE lgkm-only barrier per step
//   - gate activations via __builtin_amdgcn_rcpf (r8, +12%)
// History: r9 (4-wave full residency, 1 wave/SIMD) = no latency hiding, worse;
// r10 (cooperative persistent) = grid.sync ~60us/iter, worse. r8 structure
// + this LDS-traffic cut is the incremental path.
// ---------------------------------------------------------------------------

typedef _Float16 f16;
typedef _Float16 f16x8 __attribute__((ext_vector_type(8)));
typedef _Float16 f16x4 __attribute__((ext_vector_type(4)));
typedef float    f32x4 __attribute__((ext_vector_type(4)));

#define B_      256
#define T_      512
#define H_      256
#define G_      768      // 3*H
#define IN_RAW  75
#define KX      96       // padded input K
#define MROWS   (T_*B_)  // 131072

__device__ __forceinline__ float rcp_(float x){ return __builtin_amdgcn_rcpf(x); }
__device__ __forceinline__ float sigm(float x){ return rcp_(1.f + __expf(-x)); }
__device__ __forceinline__ float tanh_(float x){ return 1.f - 2.f*rcp_(1.f + __expf(2.f*x)); }

// barrier that waits ONLY on LDS ops (no vmcnt/expcnt drain).
__device__ __forceinline__ void bar_lds(){
  asm volatile("s_waitcnt lgkmcnt(0)" ::: "memory");
  __builtin_amdgcn_s_barrier();
  __builtin_amdgcn_sched_barrier(0);   // no hoisting of LDS reads above barrier
}

// --------------------------------------------------------------------------
// cast_x: x[b][t][j] (f32) -> xb[t*256+b][96] (fp16, j>=75 zero)
// --------------------------------------------------------------------------
__global__ __launch_bounds__(256) void cast_x(const float* __restrict__ x,
                                              f16* __restrict__ xb){
  int idx = blockIdx.x*256 + threadIdx.x;        // grid*256 == 131072*96 exact
  int row = idx / KX;
  int j   = idx - row*KX;
  int t   = row >> 8;        // row = t*256 + b
  int b   = row & 255;
  float v = (j < IN_RAW) ? x[((size_t)b*T_ + t)*IN_RAW + j] : 0.f;
  xb[idx] = (f16)v;
}

// --------------------------------------------------------------------------
// cast_w: all weight casts + fused biases. grid*256 == 730624 exact.
// --------------------------------------------------------------------------
__global__ __launch_bounds__(256) void cast_w(
    const float* __restrict__ Wih0, const float* __restrict__ Whh0,
    const float* __restrict__ Wih1, const float* __restrict__ Whh1,
    const float* __restrict__ fcW,
    const float* __restrict__ bih0, const float* __restrict__ bhh0,
    const float* __restrict__ bih1, const float* __restrict__ bhh1,
    f16* __restrict__ W0h, f16* __restrict__ Whh0h, f16* __restrict__ Wih1h,
    f16* __restrict__ Whh1h, f16* __restrict__ fcWh,
    float* __restrict__ bias0, float* __restrict__ bias1){
  int i = blockIdx.x*256 + threadIdx.x;
  if (i < 73728){ int r = i/KX, j = i - r*KX;
    W0h[i] = (f16)((j < IN_RAW) ? Wih0[r*IN_RAW + j] : 0.f); return; }
  i -= 73728;
  if (i < 196608){ Whh0h[i] = (f16)Whh0[i]; return; } i -= 196608;
  if (i < 196608){ Wih1h[i] = (f16)Wih1[i]; return; } i -= 196608;
  if (i < 196608){ Whh1h[i] = (f16)Whh1[i]; return; } i -= 196608;
  if (i < 65536){ fcWh[i] = (f16)fcW[i]; return; } i -= 65536;
  if (i < 768){ bias0[i] = bih0[i] + (i < 512 ? bhh0[i] : 0.f); return; } i -= 768;
  if (i < 768){ bias1[i] = bih1[i] + (i < 512 ? bhh1[i] : 0.f); }
}

// --------------------------------------------------------------------------
// cast_h: h1s f32 [256*256] -> hT fp16
// --------------------------------------------------------------------------
__global__ __launch_bounds__(256) void cast_h(const float* __restrict__ hs,
                                              f16* __restrict__ hT){
  int i = blockIdx.x*256 + threadIdx.x;
  hT[i] = (f16)hs[i];
}

// --------------------------------------------------------------------------
// gemm_k: out[M,N] = A[M,K](fp16) @ W[N,K]^T(fp16) + bias. 256-thread/8-wave
// standalone kernel for the prologue gemm and the fc epilogue.
// --------------------------------------------------------------------------
template<int K, int BN, bool OUTF32>
__global__ __launch_bounds__(256, 2) void gemm_k(const f16* __restrict__ A,
    const f16* __restrict__ W, const float* __restrict__ bias,
    void* __restrict__ outp, const int N){
  constexpr int NT = BN/16;
  const int tid  = threadIdx.x;
  const int wave = tid >> 6, lane = tid & 63;
  const int quad = lane >> 4, l16 = lane & 15;
  const long mbase = (long)blockIdx.x*128 + wave*32;
  const int  nbase = blockIdx.y*BN;
  f32x4 acc[2][NT] = {};
#pragma unroll 2
  for (int kc = 0; kc < K/32; ++kc){
    f16x8 a0 = *(const f16x8*)(A + (mbase +      l16)*K + kc*32 + quad*8);
    f16x8 a1 = *(const f16x8*)(A + (mbase + 16 + l16)*K + kc*32 + quad*8);
#pragma unroll
    for (int nt = 0; nt < NT; ++nt){
      f16x8 b = *(const f16x8*)(W + (long)(nbase + nt*16 + l16)*K + kc*32 + quad*8);
      acc[0][nt] = __builtin_amdgcn_mfma_f32_16x16x32_f16(a0, b, acc[0][nt], 0, 0, 0);
      acc[1][nt] = __builtin_amdgcn_mfma_f32_16x16x32_f16(a1, b, acc[1][nt], 0, 0, 0);
    }
  }
#pragma unroll
  for (int nt = 0; nt < NT; ++nt){
    const int col = nbase + nt*16 + l16;
    const float bv = bias[col];
#pragma unroll
    for (int af = 0; af < 2; ++af){
#pragma unroll
      for (int r = 0; r < 4; ++r){
        const long row = mbase + af*16 + quad*4 + r;   // D row = quad*4 + reg
        float v = acc[af][nt][r] + bv;
        if (OUTF32) ((float*)outp)[row*(long)N + col] = v;
        else        ((f16*)outp)[row*(long)N + col] = (f16)v;
      }
    }
  }
}

// --------------------------------------------------------------------------
// gemm_body128: 512-thread (8-wave) GEMM tile for the fused kernel.
// Block covers 512 rows (2 sequential 256-row tiles) x 128 cols, N=768.
// acc = 2x8 f32x4 = 64 regs -> gemm path stays well under 128 arch VGPRs.
// --------------------------------------------------------------------------
template<int K>
__device__ __forceinline__ void gemm_body128(const f16* __restrict__ A,
    const f16* __restrict__ W, const float* __restrict__ bias,
    f16* __restrict__ out, const int bx, const int by){
  const int tid  = threadIdx.x;
  const int wave = tid >> 6, lane = tid & 63;
  const int quad = lane >> 4, l16 = lane & 15;
  const int nbase = by*128;
#pragma unroll
  for (int mt = 0; mt < 2; ++mt){
    const long mbase = (long)bx*512 + mt*256 + wave*32;
    f32x4 acc[2][8] = {};
#pragma unroll 2
    for (int kc = 0; kc < K/32; ++kc){
      f16x8 a0 = *(const f16x8*)(A + (mbase +      l16)*K + kc*32 + quad*8);
      f16x8 a1 = *(const f16x8*)(A + (mbase + 16 + l16)*K + kc*32 + quad*8);
#pragma unroll
      for (int nt = 0; nt < 8; ++nt){
        f16x8 b = *(const f16x8*)(W + (long)(nbase + nt*16 + l16)*K + kc*32 + quad*8);
        acc[0][nt] = __builtin_amdgcn_mfma_f32_16x16x32_f16(a0, b, acc[0][nt], 0, 0, 0);
        acc[1][nt] = __builtin_amdgcn_mfma_f32_16x16x32_f16(a1, b, acc[1][nt], 0, 0, 0);
      }
    }
#pragma unroll
    for (int nt = 0; nt < 8; ++nt){
      const int col = nbase + nt*16 + l16;
      const float bv = bias[col];
#pragma unroll
      for (int af = 0; af < 2; ++af)
#pragma unroll
        for (int r = 0; r < 4; ++r)
          out[(mbase + af*16 + quad*4 + r)*(long)G_ + col] = (f16)(acc[af][nt][r] + bv);
    }
  }
}

// --------------------------------------------------------------------------
// scan_body: TC steps of one GRU layer, swapped-operand.
// 16 WGs x 512 thr (8 waves); WG owns batch rows [bx*16,+16).
// Wave owns gate rows [w*32,+32) of r/z/n.
//   r,z (all kc):  32 frags = 128 AGPR ("a"-pinned)
//   n s=0 (8 kc):  8 frags = 32 VGPR ("v"-pinned)          [r11]
//   n s=1 (8 kc):  streamed from nlds (64KB, A-frag order) [r11: was 128KB]
//   bn bias:       registers (was LDS)                     [r11]
// acc init: accR/accZ = gate inputs (f32), accN = bn       [r11]
// hbuf: row*512 + ((chunk ^ (row&7))<<4), double-buffered; ONE lgkm-only
// barrier/step; xg(t+1) loaded after gate math, in flight across barrier.
// --------------------------------------------------------------------------
__device__ __forceinline__ void scan_body(const f16* __restrict__ xg,
    const f16* __restrict__ Whh, const float* __restrict__ bhh,
    float* __restrict__ hstate, f16* __restrict__ out0,
    const int TC, const int bx){
  __shared__ char  hbufB[2][8192];     // 16 KB: h(t) fp16, XOR-swizzled
  __shared__ f16   nlds[32768];        // 64 KB: n-gate s=1 half, A-frag order
  const int tid  = threadIdx.x;
  const int wave = tid >> 6, lane = tid & 63;
  const int quad = lane >> 4, l16 = lane & 15;
  const int b0   = bx*16;
  const int jj   = wave*32 + quad*4;   // D-row (hidden) base; s adds 16

  // r,z A-frags -> AGPR
  f16x8 w[2][2][8];   // [s][g: r,z][kc]
#pragma unroll
  for (int s = 0; s < 2; ++s)
#pragma unroll
    for (int g = 0; g < 2; ++g)
#pragma unroll
      for (int kc = 0; kc < 8; ++kc)
        w[s][g][kc] = *(const f16x8*)(Whh + (size_t)(g*256 + wave*32 + s*16 + l16)*H_ + kc*32 + quad*8);
#pragma unroll
  for (int s = 0; s < 2; ++s)
#pragma unroll
    for (int g = 0; g < 2; ++g)
#pragma unroll
      for (int kc = 0; kc < 8; ++kc)
        asm volatile("" : "+a"(w[s][g][kc]));   // pin in AGPRs

  // n-gate s=0 half -> VGPR (32 regs), pinned
  f16x8 wn0[8];
#pragma unroll
  for (int kc = 0; kc < 8; ++kc){
    wn0[kc] = *(const f16x8*)(Whh + (size_t)(512 + wave*32 + l16)*H_ + kc*32 + quad*8);
    asm volatile("" : "+v"(wn0[kc]));
  }

  // stage nlds with the s=1 half: piece p = f*64+L, f = wave*8 + kc
#pragma unroll
  for (int i = 0; i < 8; ++i){
    const int p  = i*512 + tid;            // 4096 pieces total
    const int f  = p >> 6, L = p & 63;
    const int wv = f >> 3, kcc = f & 7;
    const int row = 512 + wv*32 + 16 + (L & 15);   // s=1
    const int k   = kcc*32 + (L >> 4)*8;
    *(f16x8*)&nlds[(size_t)p*8] = *(const f16x8*)(Whh + (size_t)row*H_ + k);
  }

  // n-gate hidden bias -> registers (accumulator init)
  f32x4 bn[2];
#pragma unroll
  for (int s = 0; s < 2; ++s)
    bn[s] = *(const f32x4*)(bhh + 512 + jj + s*16);

  // h state: lane owns (batch=l16, hidden j=jj+s*16+r)
  f32x4 h[2];
#pragma unroll
  for (int s = 0; s < 2; ++s){
    h[s] = *(const f32x4*)(hstate + (size_t)(b0 + l16)*H_ + jj + s*16);
    f16x4 hh;
#pragma unroll
    for (int r = 0; r < 4; ++r) hh[r] = (f16)h[s][r];
    const int ch = wave*4 + s*2 + (quad>>1);                // 16B chunk index
    *(f16x4*)&hbufB[0][l16*512 + ((ch ^ (l16&7))<<4) + ((quad&1)<<3)] = hh;
  }

  // per-lane xg base: row = b0+l16, cols jj + {g*256, s*16}
  const f16* xgl = xg + (size_t)(b0 + l16)*G_ + jj;
  f16x4 cur[6];
#pragma unroll
  for (int s = 0; s < 2; ++s)
#pragma unroll
    for (int g = 0; g < 3; ++g)
      cur[s*3+g] = *(const f16x4*)(xgl + g*256 + s*16);

  __syncthreads();   // one-time full drain: hbuf[0], nlds staged

  for (int t = 0; t < TC; ++t){
    const int pb = t & 1;
    // acc init: r,z from gate inputs; n from bias (accumulates in f32, same
    // value as post-add; r5/r6 verified this ordering passes refcheck)
    f32x4 acc[2][3];
#pragma unroll
    for (int s = 0; s < 2; ++s){
#pragma unroll
      for (int r = 0; r < 4; ++r){
        acc[s][0][r] = (float)cur[s*3+0][r];
        acc[s][1][r] = (float)cur[s*3+1][r];
      }
      acc[s][2] = bn[s];
    }
#pragma unroll
    for (int kc = 0; kc < 8; ++kc){
      // B-frag: h[batch=l16][k=kc*32+quad*8], swizzled chunk = kc*4+quad
      f16x8 hf = *(const f16x8*)&hbufB[pb][l16*512 + ((((kc<<2)|quad) ^ (l16&7))<<4)];
#pragma unroll
      for (int s = 0; s < 2; ++s){
        acc[s][0] = __builtin_amdgcn_mfma_f32_16x16x32_f16(w[s][0][kc], hf, acc[s][0], 0,0,0);
        acc[s][1] = __builtin_amdgcn_mfma_f32_16x16x32_f16(w[s][1][kc], hf, acc[s][1], 0,0,0);
        f16x8 nf = (s == 0) ? wn0[kc]
                 : *(const f16x8*)&nlds[(size_t)(((wave<<3)|kc)*64 + lane)*8];
        acc[s][2] = __builtin_amdgcn_mfma_f32_16x16x32_f16(nf, hf, acc[s][2], 0,0,0);
      }
    }
    f16x4 hh[2];
#pragma unroll
    for (int s = 0; s < 2; ++s){
#pragma unroll
      for (int r = 0; r < 4; ++r){
        float rg = sigm(acc[s][0][r]);
        float zg = sigm(acc[s][1][r]);
        float ng = tanh_((float)cur[s*3+2][r] + rg*acc[s][2][r]);
        float hv = ng + zg*(h[s][r] - ng);
        h[s][r] = hv;
        hh[s][r] = (f16)hv;
      }
    }
    if (t+1 < TC){  // load t+1 gates into cur (old cur fully consumed above);
      const f16* xn_ = xgl + (size_t)(t+1)*(B_*G_);   // stays in flight across
#pragma unroll                                        // the lgkm-only barrier
      for (int s = 0; s < 2; ++s)
#pragma unroll
        for (int g = 0; g < 3; ++g)
          cur[s*3+g] = *(const f16x4*)(xn_ + g*256 + s*16);
    }
#pragma unroll
    for (int s = 0; s < 2; ++s){
      const int ch = wave*4 + s*2 + (quad>>1);
      *(f16x4*)&hbufB[pb^1][l16*512 + ((ch ^ (l16&7))<<4) + ((quad&1)<<3)] = hh[s];
      if (out0)
        *(f16x4*)(out0 + ((size_t)t*B_ + b0 + l16)*H_ + jj + s*16) = hh[s];
    }
    bar_lds();   // h(t) visible in hbuf[pb^1]; VMEM ops NOT drained
  }

#pragma unroll
  for (int s = 0; s < 2; ++s)
    *(f32x4*)(hstate + (size_t)(b0 + l16)*H_ + jj + s*16) = h[s];
}

// --------------------------------------------------------------------------
// fused: [scan L0] || [scan L1] || [gemm0 next chunk] || [gemm1 prev chunk]
// blocks: [0,16) L0, [16,32) L1, [32,32+3TC) gemm0, [32+3TC,32+6TC) gemm1.
// mask: bit0 L0, bit1 L1, bit2 gemm0, bit3 gemm1.  grid = 32+6TC (<=224).
// --------------------------------------------------------------------------
__global__ __launch_bounds__(512)
__attribute__((amdgpu_waves_per_eu(2, 2)))
void fused(
    const f16* __restrict__ xg0, const f16* __restrict__ Whh0,
    const float* __restrict__ bhh0, float* __restrict__ h0s,
    f16* __restrict__ out0w,
    const f16* __restrict__ xg1, const f16* __restrict__ Whh1,
    const float* __restrict__ bhh1, float* __restrict__ h1s,
    const f16* __restrict__ g0A, const f16* __restrict__ g0W,
    const float* __restrict__ g0b, f16* __restrict__ g0out,
    const f16* __restrict__ g1A, const f16* __restrict__ g1W,
    const float* __restrict__ g1b, f16* __restrict__ g1out,
    const int TC, const int mask){
  const int bid = blockIdx.x;
  if (bid < 16){
    if (!(mask & 1)) return;
    scan_body(xg0, Whh0, bhh0, h0s, out0w, TC, bid);
  } else if (bid < 32){
    if (!(mask & 2)) return;
    scan_body(xg1, Whh1, bhh1, h1s, (f16*)nullptr, TC, bid - 16);
  } else {
    int g = bid - 32;
    const int RB = TC/2;                 // 512-row blocks per gemm
    if (g < 3*TC){
      if (!(mask & 4)) return;
      gemm_body128<96>(g0A, g0W, g0b, g0out, g % RB, g / RB);
    } else {
      g -= 3*TC;
      if (!(mask & 8)) return;
      gemm_body128<256>(g1A, g1W, g1b, g1out, g % RB, g / RB);
    }
  }
}

// --------------------------------------------------------------------------
extern "C" void kernel_launch(void* const* d_in, const int* in_sizes, int n_in,
                              void* d_out, int out_size, void* d_ws, size_t ws_size,
                              hipStream_t stream){
  (void)in_sizes; (void)n_in; (void)out_size;
  const float* x    = (const float*)d_in[0];
  const float* Wih0 = (const float*)d_in[1];
  const float* Whh0 = (const float*)d_in[2];
  const float* bih0 = (const float*)d_in[3];
  const float* bhh0 = (const float*)d_in[4];
  const float* Wih1 = (const float*)d_in[5];
  const float* Whh1 = (const float*)d_in[6];
  const float* bih1 = (const float*)d_in[7];
  const float* bhh1 = (const float*)d_in[8];
  const float* fcW  = (const float*)d_in[9];
  const float* fcb  = (const float*)d_in[10];

  char* ws = (char*)d_ws;
  size_t off = 0;
  auto alloc = [&](size_t bytes) -> void* {
    void* p = ws + off; off += (bytes + 255) & ~(size_t)255; return p;
  };
  f16*   xb    = (f16*)  alloc((size_t)MROWS*KX*2);   // 25.2 MB
  f16*   W0h   = (f16*)  alloc((size_t)G_*KX*2);
  f16*   Whh0h = (f16*)  alloc((size_t)G_*H_*2);
  f16*   Wih1h = (f16*)  alloc((size_t)G_*H_*2);
  f16*   Whh1h = (f16*)  alloc((size_t)G_*H_*2);
  f16*   fcWh  = (f16*)  alloc((size_t)H_*H_*2);
  float* bias0 = (float*)alloc(G_*4);
  float* bias1 = (float*)alloc(G_*4);
  float* h0s   = (float*)alloc((size_t)B_*H_*4);      // h-state, both layers
  float* h1s   = (float*)alloc((size_t)B_*H_*4);      //   (adjacent: one memset)
  f16*   hTh   = (f16*)  alloc((size_t)B_*H_*2);
  const size_t fixed = off;

  // TC=32: double-buffered xg (both layers) + out0. Per-TC bytes:
  // 4*B*G*2 + 2*B*H*2 = 1,835,008. Fallback shrink if ws is tight.
  int TC = 32;
  while (TC > 8 && fixed + (size_t)TC*1835008 + 1024 > ws_size) TC >>= 1;
  f16* xg0[2], *xg1[2], *out0[2];
  xg0[0]  = (f16*)alloc((size_t)TC*B_*G_*2);
  xg0[1]  = (f16*)alloc((size_t)TC*B_*G_*2);
  xg1[0]  = (f16*)alloc((size_t)TC*B_*G_*2);
  xg1[1]  = (f16*)alloc((size_t)TC*B_*G_*2);
  out0[0] = (f16*)alloc((size_t)TC*B_*H_*2);
  out0[1] = (f16*)alloc((size_t)TC*B_*H_*2);
  const int nc = T_ / TC;

  hipMemsetAsync(h0s, 0, (size_t)B_*H_*4*2, stream);  // zero h0s+h1s (adjacent)
  hipLaunchKernelGGL(cast_x, dim3(49152), dim3(256), 0, stream, x, xb);
  hipLaunchKernelGGL(cast_w, dim3(2854), dim3(256), 0, stream,
                     Wih0, Whh0, Wih1, Whh1, fcW, bih0, bhh0, bih1, bhh1,
                     W0h, Whh0h, Wih1h, Whh1h, fcWh, bias0, bias1);

  // prologue: xg0[0] = xb[chunk 0] @ W_ih0^T + bias0
  hipLaunchKernelGGL((gemm_k<96,192,false>), dim3(TC*2,4), dim3(256), 0, stream,
                     xb, W0h, bias0, (void*)xg0[0], G_);

  const dim3 grid(32 + 6*TC);
  for (int i = 0; i <= nc + 1; ++i){
    int mask = 0;
    if (i < nc)            mask |= 1;   // L0 scans chunk i
    if (i >= 2)            mask |= 2;   // L1 scans chunk i-2
    if (i + 1 < nc)        mask |= 4;   // gemm0 builds chunk i+1
    if (i >= 1 && i <= nc) mask |= 8;   // gemm1 builds chunk i-1
    hipLaunchKernelGGL(fused, grid, dim3(512), 0, stream,
                       xg0[i&1], Whh0h, bhh0, h0s, out0[i&1],
                       xg1[i&1], Whh1h, bhh1, h1s,
                       xb + (size_t)(i+1)*TC*B_*KX, W0h, bias0, xg0[(i+1)&1],
                       out0[(i+1)&1], Wih1h, bias1, xg1[(i+1)&1],
                       TC, mask);
  }

  // embedding = hT @ fc_W^T + fc_b (f32 out)
  hipLaunchKernelGGL(cast_h, dim3(256), dim3(256), 0, stream, h1s, hTh);
  hipLaunchKernelGGL((gemm_k<256,64,true>), dim3(2,4), dim3(256), 0, stream,
                     hTh, fcWh, fcb, d_out, H_);
}

// Round 12
// 2018.347 us; speedup vs baseline: 1.3954x; 1.0920x over previous
//
#include <hip/hip_runtime.h>
#include <hip/hip_bf16.h>
#include <stdint.h>
#include <stddef.h>

// ---------------------------------------------------------------------------
// GRUEncoder: x[256,512,25,3] f32 -> 2-layer GRU(H=256) -> fc(hT) -> [256,256] f32
//
// Fused pipelined schedule (chunk = TC steps, 2-chunk layer skew):
//   cast_x ; cast_w ; gemm0(chunk0)
//   for i in 0..nc+1:   ONE launch: [scan L0 chunk i] || [scan L1 chunk i-2]
//                                   || [gemm0 chunk i+1] || [gemm1 chunk i-1]
//   cast_h ; fc gemm
//
// Scan, swapped MFMA operands: D[gate rows x batch cols] = Whh * h.
//   - r,z weights pinned in 128 AGPR ("a")
//   - n-gate s=0 half pinned in 32 VGPR, s=1 half streamed from 64KB LDS
//   - bn bias in registers, seeds accN (no LDS reads for bias)
//   - hbuf XOR-swizzled, double-buffered, ONE lgkm-only barrier per step
//   - gate activations via __builtin_amdgcn_rcpf
//
// r12 lesson (from r11's 90.7->122us regression): do NOT seed accR/accZ from
// the xg gate inputs -- that makes the FIRST MFMA depend on the xg prefetch
// loads, moving the vmcnt wait from after the MFMA phase (latency hidden
// under 48 MFMAs) to before it (latency exposed). Gate inputs must be
// consumed only in the gate-VALU phase, as in r8.
// ---------------------------------------------------------------------------

typedef _Float16 f16;
typedef _Float16 f16x8 __attribute__((ext_vector_type(8)));
typedef _Float16 f16x4 __attribute__((ext_vector_type(4)));
typedef float    f32x4 __attribute__((ext_vector_type(4)));

#define B_      256
#define T_      512
#define H_      256
#define G_      768      // 3*H
#define IN_RAW  75
#define KX      96       // padded input K
#define MROWS   (T_*B_)  // 131072

__device__ __forceinline__ float rcp_(float x){ return __builtin_amdgcn_rcpf(x); }
__device__ __forceinline__ float sigm(float x){ return rcp_(1.f + __expf(-x)); }
__device__ __forceinline__ float tanh_(float x){ return 1.f - 2.f*rcp_(1.f + __expf(2.f*x)); }

// barrier that waits ONLY on LDS ops (no vmcnt/expcnt drain).
__device__ __forceinline__ void bar_lds(){
  asm volatile("s_waitcnt lgkmcnt(0)" ::: "memory");
  __builtin_amdgcn_s_barrier();
  __builtin_amdgcn_sched_barrier(0);   // no hoisting of LDS reads above barrier
}

// --------------------------------------------------------------------------
// cast_x: x[b][t][j] (f32) -> xb[t*256+b][96] (fp16, j>=75 zero)
// --------------------------------------------------------------------------
__global__ __launch_bounds__(256) void cast_x(const float* __restrict__ x,
                                              f16* __restrict__ xb){
  int idx = blockIdx.x*256 + threadIdx.x;        // grid*256 == 131072*96 exact
  int row = idx / KX;
  int j   = idx - row*KX;
  int t   = row >> 8;        // row = t*256 + b
  int b   = row & 255;
  float v = (j < IN_RAW) ? x[((size_t)b*T_ + t)*IN_RAW + j] : 0.f;
  xb[idx] = (f16)v;
}

// --------------------------------------------------------------------------
// cast_w: all weight casts + fused biases. grid*256 == 730624 exact.
// --------------------------------------------------------------------------
__global__ __launch_bounds__(256) void cast_w(
    const float* __restrict__ Wih0, const float* __restrict__ Whh0,
    const float* __restrict__ Wih1, const float* __restrict__ Whh1,
    const float* __restrict__ fcW,
    const float* __restrict__ bih0, const float* __restrict__ bhh0,
    const float* __restrict__ bih1, const float* __restrict__ bhh1,
    f16* __restrict__ W0h, f16* __restrict__ Whh0h, f16* __restrict__ Wih1h,
    f16* __restrict__ Whh1h, f16* __restrict__ fcWh,
    float* __restrict__ bias0, float* __restrict__ bias1){
  int i = blockIdx.x*256 + threadIdx.x;
  if (i < 73728){ int r = i/KX, j = i - r*KX;
    W0h[i] = (f16)((j < IN_RAW) ? Wih0[r*IN_RAW + j] : 0.f); return; }
  i -= 73728;
  if (i < 196608){ Whh0h[i] = (f16)Whh0[i]; return; } i -= 196608;
  if (i < 196608){ Wih1h[i] = (f16)Wih1[i]; return; } i -= 196608;
  if (i < 196608){ Whh1h[i] = (f16)Whh1[i]; return; } i -= 196608;
  if (i < 65536){ fcWh[i] = (f16)fcW[i]; return; } i -= 65536;
  if (i < 768){ bias0[i] = bih0[i] + (i < 512 ? bhh0[i] : 0.f); return; } i -= 768;
  if (i < 768){ bias1[i] = bih1[i] + (i < 512 ? bhh1[i] : 0.f); }
}

// --------------------------------------------------------------------------
// cast_h: h1s f32 [256*256] -> hT fp16
// --------------------------------------------------------------------------
__global__ __launch_bounds__(256) void cast_h(const float* __restrict__ hs,
                                              f16* __restrict__ hT){
  int i = blockIdx.x*256 + threadIdx.x;
  hT[i] = (f16)hs[i];
}

// --------------------------------------------------------------------------
// gemm_k: out[M,N] = A[M,K](fp16) @ W[N,K]^T(fp16) + bias. 256-thread/8-wave
// standalone kernel for the prologue gemm and the fc epilogue.
// --------------------------------------------------------------------------
template<int K, int BN, bool OUTF32>
__global__ __launch_bounds__(256, 2) void gemm_k(const f16* __restrict__ A,
    const f16* __restrict__ W, const float* __restrict__ bias,
    void* __restrict__ outp, const int N){
  constexpr int NT = BN/16;
  const int tid  = threadIdx.x;
  const int wave = tid >> 6, lane = tid & 63;
  const int quad = lane >> 4, l16 = lane & 15;
  const long mbase = (long)blockIdx.x*128 + wave*32;
  const int  nbase = blockIdx.y*BN;
  f32x4 acc[2][NT] = {};
#pragma unroll 2
  for (int kc = 0; kc < K/32; ++kc){
    f16x8 a0 = *(const f16x8*)(A + (mbase +      l16)*K + kc*32 + quad*8);
    f16x8 a1 = *(const f16x8*)(A + (mbase + 16 + l16)*K + kc*32 + quad*8);
#pragma unroll
    for (int nt = 0; nt < NT; ++nt){
      f16x8 b = *(const f16x8*)(W + (long)(nbase + nt*16 + l16)*K + kc*32 + quad*8);
      acc[0][nt] = __builtin_amdgcn_mfma_f32_16x16x32_f16(a0, b, acc[0][nt], 0, 0, 0);
      acc[1][nt] = __builtin_amdgcn_mfma_f32_16x16x32_f16(a1, b, acc[1][nt], 0, 0, 0);
    }
  }
#pragma unroll
  for (int nt = 0; nt < NT; ++nt){
    const int col = nbase + nt*16 + l16;
    const float bv = bias[col];
#pragma unroll
    for (int af = 0; af < 2; ++af){
#pragma unroll
      for (int r = 0; r < 4; ++r){
        const long row = mbase + af*16 + quad*4 + r;   // D row = quad*4 + reg
        float v = acc[af][nt][r] + bv;
        if (OUTF32) ((float*)outp)[row*(long)N + col] = v;
        else        ((f16*)outp)[row*(long)N + col] = (f16)v;
      }
    }
  }
}

// --------------------------------------------------------------------------
// gemm_body128: 512-thread (8-wave) GEMM tile for the fused kernel.
// Block covers 512 rows (2 sequential 256-row tiles) x 128 cols, N=768.
// acc = 2x8 f32x4 = 64 regs -> gemm path stays well under 128 arch VGPRs.
// --------------------------------------------------------------------------
template<int K>
__device__ __forceinline__ void gemm_body128(const f16* __restrict__ A,
    const f16* __restrict__ W, const float* __restrict__ bias,
    f16* __restrict__ out, const int bx, const int by){
  const int tid  = threadIdx.x;
  const int wave = tid >> 6, lane = tid & 63;
  const int quad = lane >> 4, l16 = lane & 15;
  const int nbase = by*128;
#pragma unroll
  for (int mt = 0; mt < 2; ++mt){
    const long mbase = (long)bx*512 + mt*256 + wave*32;
    f32x4 acc[2][8] = {};
#pragma unroll 2
    for (int kc = 0; kc < K/32; ++kc){
      f16x8 a0 = *(const f16x8*)(A + (mbase +      l16)*K + kc*32 + quad*8);
      f16x8 a1 = *(const f16x8*)(A + (mbase + 16 + l16)*K + kc*32 + quad*8);
#pragma unroll
      for (int nt = 0; nt < 8; ++nt){
        f16x8 b = *(const f16x8*)(W + (long)(nbase + nt*16 + l16)*K + kc*32 + quad*8);
        acc[0][nt] = __builtin_amdgcn_mfma_f32_16x16x32_f16(a0, b, acc[0][nt], 0, 0, 0);
        acc[1][nt] = __builtin_amdgcn_mfma_f32_16x16x32_f16(a1, b, acc[1][nt], 0, 0, 0);
      }
    }
#pragma unroll
    for (int nt = 0; nt < 8; ++nt){
      const int col = nbase + nt*16 + l16;
      const float bv = bias[col];
#pragma unroll
      for (int af = 0; af < 2; ++af)
#pragma unroll
        for (int r = 0; r < 4; ++r)
          out[(mbase + af*16 + quad*4 + r)*(long)G_ + col] = (f16)(acc[af][nt][r] + bv);
    }
  }
}

// --------------------------------------------------------------------------
// scan_body: TC steps of one GRU layer, swapped-operand. r8 dataflow.
// 16 WGs x 512 thr (8 waves); WG owns batch rows [bx*16,+16).
// Wave owns gate rows [w*32,+32) of r/z/n.
//   r,z (all kc):  32 frags = 128 AGPR ("a"-pinned)
//   n s=0 (8 kc):  8 frags = 32 VGPR ("v"-pinned)
//   n s=1 (8 kc):  streamed from nlds (64KB, A-frag order)
//   bn bias:       registers, seeds accN (register-only, no dependency)
// acc r/z: ZERO-init; gate inputs added in the gate-VALU phase only, so the
// xg prefetch's vmcnt wait stays AFTER the MFMA phase (r12 fix).
// hbuf: row*512 + ((chunk ^ (row&7))<<4), double-buffered; ONE lgkm-only
// barrier/step; xg(t+1) loaded after gate math, in flight across barrier.
// --------------------------------------------------------------------------
__device__ __forceinline__ void scan_body(const f16* __restrict__ xg,
    const f16* __restrict__ Whh, const float* __restrict__ bhh,
    float* __restrict__ hstate, f16* __restrict__ out0,
    const int TC, const int bx){
  __shared__ char  hbufB[2][8192];     // 16 KB: h(t) fp16, XOR-swizzled
  __shared__ f16   nlds[32768];        // 64 KB: n-gate s=1 half, A-frag order
  const int tid  = threadIdx.x;
  const int wave = tid >> 6, lane = tid & 63;
  const int quad = lane >> 4, l16 = lane & 15;
  const int b0   = bx*16;
  const int jj   = wave*32 + quad*4;   // D-row (hidden) base; s adds 16

  // r,z A-frags -> AGPR
  f16x8 w[2][2][8];   // [s][g: r,z][kc]
#pragma unroll
  for (int s = 0; s < 2; ++s)
#pragma unroll
    for (int g = 0; g < 2; ++g)
#pragma unroll
      for (int kc = 0; kc < 8; ++kc)
        w[s][g][kc] = *(const f16x8*)(Whh + (size_t)(g*256 + wave*32 + s*16 + l16)*H_ + kc*32 + quad*8);
#pragma unroll
  for (int s = 0; s < 2; ++s)
#pragma unroll
    for (int g = 0; g < 2; ++g)
#pragma unroll
      for (int kc = 0; kc < 8; ++kc)
        asm volatile("" : "+a"(w[s][g][kc]));   // pin in AGPRs

  // n-gate s=0 half -> VGPR (32 regs), pinned
  f16x8 wn0[8];
#pragma unroll
  for (int kc = 0; kc < 8; ++kc){
    wn0[kc] = *(const f16x8*)(Whh + (size_t)(512 + wave*32 + l16)*H_ + kc*32 + quad*8);
    asm volatile("" : "+v"(wn0[kc]));
  }

  // stage nlds with the s=1 half: piece p = f*64+L, f = wave*8 + kc
#pragma unroll
  for (int i = 0; i < 8; ++i){
    const int p  = i*512 + tid;            // 4096 pieces total
    const int f  = p >> 6, L = p & 63;
    const int wv = f >> 3, kcc = f & 7;
    const int row = 512 + wv*32 + 16 + (L & 15);   // s=1
    const int k   = kcc*32 + (L >> 4)*8;
    *(f16x8*)&nlds[(size_t)p*8] = *(const f16x8*)(Whh + (size_t)row*H_ + k);
  }

  // n-gate hidden bias -> registers (accumulator seed; register-only)
  f32x4 bn[2];
#pragma unroll
  for (int s = 0; s < 2; ++s)
    bn[s] = *(const f32x4*)(bhh + 512 + jj + s*16);

  // h state: lane owns (batch=l16, hidden j=jj+s*16+r)
  f32x4 h[2];
#pragma unroll
  for (int s = 0; s < 2; ++s){
    h[s] = *(const f32x4*)(hstate + (size_t)(b0 + l16)*H_ + jj + s*16);
    f16x4 hh;
#pragma unroll
    for (int r = 0; r < 4; ++r) hh[r] = (f16)h[s][r];
    const int ch = wave*4 + s*2 + (quad>>1);                // 16B chunk index
    *(f16x4*)&hbufB[0][l16*512 + ((ch ^ (l16&7))<<4) + ((quad&1)<<3)] = hh;
  }

  // per-lane xg base: row = b0+l16, cols jj + {g*256, s*16}
  const f16* xgl = xg + (size_t)(b0 + l16)*G_ + jj;
  f16x4 cur[6];
#pragma unroll
  for (int s = 0; s < 2; ++s)
#pragma unroll
    for (int g = 0; g < 3; ++g)
      cur[s*3+g] = *(const f16x4*)(xgl + g*256 + s*16);

  __syncthreads();   // one-time full drain: hbuf[0], nlds staged

  for (int t = 0; t < TC; ++t){
    const int pb = t & 1;
    f32x4 acc[2][3];
#pragma unroll
    for (int s = 0; s < 2; ++s){
      acc[s][0] = (f32x4){0.f,0.f,0.f,0.f};
      acc[s][1] = (f32x4){0.f,0.f,0.f,0.f};
      acc[s][2] = bn[s];                 // register seed, no VMEM dependency
    }
#pragma unroll
    for (int kc = 0; kc < 8; ++kc){
      // B-frag: h[batch=l16][k=kc*32+quad*8], swizzled chunk = kc*4+quad
      f16x8 hf = *(const f16x8*)&hbufB[pb][l16*512 + ((((kc<<2)|quad) ^ (l16&7))<<4)];
#pragma unroll
      for (int s = 0; s < 2; ++s){
        acc[s][0] = __builtin_amdgcn_mfma_f32_16x16x32_f16(w[s][0][kc], hf, acc[s][0], 0,0,0);
        acc[s][1] = __builtin_amdgcn_mfma_f32_16x16x32_f16(w[s][1][kc], hf, acc[s][1], 0,0,0);
        f16x8 nf = (s == 0) ? wn0[kc]
                 : *(const f16x8*)&nlds[(size_t)(((wave<<3)|kc)*64 + lane)*8];
        acc[s][2] = __builtin_amdgcn_mfma_f32_16x16x32_f16(nf, hf, acc[s][2], 0,0,0);
      }
    }
    f16x4 hh[2];
#pragma unroll
    for (int s = 0; s < 2; ++s){
#pragma unroll
      for (int r = 0; r < 4; ++r){
        float rg = sigm((float)cur[s*3+0][r] + acc[s][0][r]);
        float zg = sigm((float)cur[s*3+1][r] + acc[s][1][r]);
        float ng = tanh_((float)cur[s*3+2][r] + rg*acc[s][2][r]);
        float hv = ng + zg*(h[s][r] - ng);
        h[s][r] = hv;
        hh[s][r] = (f16)hv;
      }
    }
    if (t+1 < TC){  // load t+1 gates into cur (old cur fully consumed above);
      const f16* xn_ = xgl + (size_t)(t+1)*(B_*G_);   // stays in flight across
#pragma unroll                                        // the lgkm-only barrier
      for (int s = 0; s < 2; ++s)
#pragma unroll
        for (int g = 0; g < 3; ++g)
          cur[s*3+g] = *(const f16x4*)(xn_ + g*256 + s*16);
    }
#pragma unroll
    for (int s = 0; s < 2; ++s){
      const int ch = wave*4 + s*2 + (quad>>1);
      *(f16x4*)&hbufB[pb^1][l16*512 + ((ch ^ (l16&7))<<4) + ((quad&1)<<3)] = hh[s];
      if (out0)
        *(f16x4*)(out0 + ((size_t)t*B_ + b0 + l16)*H_ + jj + s*16) = hh[s];
    }
    bar_lds();   // h(t) visible in hbuf[pb^1]; VMEM ops NOT drained
  }

#pragma unroll
  for (int s = 0; s < 2; ++s)
    *(f32x4*)(hstate + (size_t)(b0 + l16)*H_ + jj + s*16) = h[s];
}

// --------------------------------------------------------------------------
// fused: [scan L0] || [scan L1] || [gemm0 next chunk] || [gemm1 prev chunk]
// blocks: [0,16) L0, [16,32) L1, [32,32+3TC) gemm0, [32+3TC,32+6TC) gemm1.
// mask: bit0 L0, bit1 L1, bit2 gemm0, bit3 gemm1.  grid = 32+6TC (<=224).
// --------------------------------------------------------------------------
__global__ __launch_bounds__(512)
__attribute__((amdgpu_waves_per_eu(2, 2)))
void fused(
    const f16* __restrict__ xg0, const f16* __restrict__ Whh0,
    const float* __restrict__ bhh0, float* __restrict__ h0s,
    f16* __restrict__ out0w,
    const f16* __restrict__ xg1, const f16* __restrict__ Whh1,
    const float* __restrict__ bhh1, float* __restrict__ h1s,
    const f16* __restrict__ g0A, const f16* __restrict__ g0W,
    const float* __restrict__ g0b, f16* __restrict__ g0out,
    const f16* __restrict__ g1A, const f16* __restrict__ g1W,
    const float* __restrict__ g1b, f16* __restrict__ g1out,
    const int TC, const int mask){
  const int bid = blockIdx.x;
  if (bid < 16){
    if (!(mask & 1)) return;
    scan_body(xg0, Whh0, bhh0, h0s, out0w, TC, bid);
  } else if (bid < 32){
    if (!(mask & 2)) return;
    scan_body(xg1, Whh1, bhh1, h1s, (f16*)nullptr, TC, bid - 16);
  } else {
    int g = bid - 32;
    const int RB = TC/2;                 // 512-row blocks per gemm
    if (g < 3*TC){
      if (!(mask & 4)) return;
      gemm_body128<96>(g0A, g0W, g0b, g0out, g % RB, g / RB);
    } else {
      g -= 3*TC;
      if (!(mask & 8)) return;
      gemm_body128<256>(g1A, g1W, g1b, g1out, g % RB, g / RB);
    }
  }
}

// --------------------------------------------------------------------------
extern "C" void kernel_launch(void* const* d_in, const int* in_sizes, int n_in,
                              void* d_out, int out_size, void* d_ws, size_t ws_size,
                              hipStream_t stream){
  (void)in_sizes; (void)n_in; (void)out_size;
  const float* x    = (const float*)d_in[0];
  const float* Wih0 = (const float*)d_in[1];
  const float* Whh0 = (const float*)d_in[2];
  const float* bih0 = (const float*)d_in[3];
  const float* bhh0 = (const float*)d_in[4];
  const float* Wih1 = (const float*)d_in[5];
  const float* Whh1 = (const float*)d_in[6];
  const float* bih1 = (const float*)d_in[7];
  const float* bhh1 = (const float*)d_in[8];
  const float* fcW  = (const float*)d_in[9];
  const float* fcb  = (const float*)d_in[10];

  char* ws = (char*)d_ws;
  size_t off = 0;
  auto alloc = [&](size_t bytes) -> void* {
    void* p = ws + off; off += (bytes + 255) & ~(size_t)255; return p;
  };
  f16*   xb    = (f16*)  alloc((size_t)MROWS*KX*2);   // 25.2 MB
  f16*   W0h   = (f16*)  alloc((size_t)G_*KX*2);
  f16*   Whh0h = (f16*)  alloc((size_t)G_*H_*2);
  f16*   Wih1h = (f16*)  alloc((size_t)G_*H_*2);
  f16*   Whh1h = (f16*)  alloc((size_t)G_*H_*2);
  f16*   fcWh  = (f16*)  alloc((size_t)H_*H_*2);
  float* bias0 = (float*)alloc(G_*4);
  float* bias1 = (float*)alloc(G_*4);
  float* h0s   = (float*)alloc((size_t)B_*H_*4);      // h-state, both layers
  float* h1s   = (float*)alloc((size_t)B_*H_*4);      //   (adjacent: one memset)
  f16*   hTh   = (f16*)  alloc((size_t)B_*H_*2);
  const size_t fixed = off;

  // TC=32: double-buffered xg (both layers) + out0. Per-TC bytes:
  // 4*B*G*2 + 2*B*H*2 = 1,835,008. Fallback shrink if ws is tight.
  int TC = 32;
  while (TC > 8 && fixed + (size_t)TC*1835008 + 1024 > ws_size) TC >>= 1;
  f16* xg0[2], *xg1[2], *out0[2];
  xg0[0]  = (f16*)alloc((size_t)TC*B_*G_*2);
  xg0[1]  = (f16*)alloc((size_t)TC*B_*G_*2);
  xg1[0]  = (f16*)alloc((size_t)TC*B_*G_*2);
  xg1[1]  = (f16*)alloc((size_t)TC*B_*G_*2);
  out0[0] = (f16*)alloc((size_t)TC*B_*H_*2);
  out0[1] = (f16*)alloc((size_t)TC*B_*H_*2);
  const int nc = T_ / TC;

  hipMemsetAsync(h0s, 0, (size_t)B_*H_*4*2, stream);  // zero h0s+h1s (adjacent)
  hipLaunchKernelGGL(cast_x, dim3(49152), dim3(256), 0, stream, x, xb);
  hipLaunchKernelGGL(cast_w, dim3(2854), dim3(256), 0, stream,
                     Wih0, Whh0, Wih1, Whh1, fcW, bih0, bhh0, bih1, bhh1,
                     W0h, Whh0h, Wih1h, Whh1h, fcWh, bias0, bias1);

  // prologue: xg0[0] = xb[chunk 0] @ W_ih0^T + bias0
  hipLaunchKernelGGL((gemm_k<96,192,false>), dim3(TC*2,4), dim3(256), 0, stream,
                     xb, W0h, bias0, (void*)xg0[0], G_);

  const dim3 grid(32 + 6*TC);
  for (int i = 0; i <= nc + 1; ++i){
    int mask = 0;
    if (i < nc)            mask |= 1;   // L0 scans chunk i
    if (i >= 2)            mask |= 2;   // L1 scans chunk i-2
    if (i + 1 < nc)        mask |= 4;   // gemm0 builds chunk i+1
    if (i >= 1 && i <= nc) mask |= 8;   // gemm1 builds chunk i-1
    hipLaunchKernelGGL(fused, grid, dim3(512), 0, stream,
                       xg0[i&1], Whh0h, bhh0, h0s, out0[i&1],
                       xg1[i&1], Whh1h, bhh1, h1s,
                       xb + (size_t)(i+1)*TC*B_*KX, W0h, bias0, xg0[(i+1)&1],
                       out0[(i+1)&1], Wih1h, bias1, xg1[(i+1)&1],
                       TC, mask);
  }

  // embedding = hT @ fc_W^T + fc_b (f32 out)
  hipLaunchKernelGGL(cast_h, dim3(256), dim3(256), 0, stream, h1s, hTh);
  hipLaunchKernelGGL((gemm_k<256,64,true>), dim3(2,4), dim3(256), 0, stream,
                     hTh, fcWh, fcb, d_out, H_);
}

// Round 13
// 1687.752 us; speedup vs baseline: 1.6687x; 1.1959x over previous
//
#include <hip/hip_runtime.h>
#include <hip/hip_bf16.h>
#include <stdint.h>
#include <stddef.h>

// ---------------------------------------------------------------------------
// GRUEncoder: x[256,512,25,3] f32 -> 2-layer GRU(H=256) -> fc(hT) -> [256,256] f32
//
// Fused pipelined schedule (chunk = TC steps, 2-chunk layer skew):
//   cast_x ; cast_w ; gemm0(chunk0)
//   for i in 0..nc+1:   ONE launch: [scan L0 chunk i] || [scan L1 chunk i-2]
//                                   || [gemm0 chunk i+1] || [gemm1 chunk i-1]
//   cast_h ; fc gemm
//
// Scan step body = r8 EXACTLY (verified best: 90.7us/chunk32, 1688us total):
//   - r,z weights pinned in 128 AGPR ("a"); all other VGPRs left FREE
//     (r11/r12 proved: pinning ANY extra regs costs more in scheduling
//      freedom than the saved LDS traffic is worth -- step is latency-bound)
//   - n-gate streamed from 128KB LDS; bias from LDS
//   - hbuf XOR-swizzled, double-buffered, ONE lgkm-only barrier per step
//   - xg(t+1) prefetched after gate math, in flight across the barrier
//   - activations via __builtin_amdgcn_rcpf
//
// r13 change: TC=64 preferred (fallback 32 => byte-identical r8). Halves the
// dispatch count 18->10, amortizing per-dispatch scan re-init (weights->AGPR
// +LDS, h round-trip, ~5-8us/WG). Fused grid kept at 224 blocks (<=256 CUs,
// co-residency guaranteed): gemm block count fixed at 96/gemm, each block
// iterates TC/32 row-super-tiles internally.
// ---------------------------------------------------------------------------

typedef _Float16 f16;
typedef _Float16 f16x8 __attribute__((ext_vector_type(8)));
typedef _Float16 f16x4 __attribute__((ext_vector_type(4)));
typedef float    f32x4 __attribute__((ext_vector_type(4)));

#define B_      256
#define T_      512
#define H_      256
#define G_      768      // 3*H
#define IN_RAW  75
#define KX      96       // padded input K
#define MROWS   (T_*B_)  // 131072

__device__ __forceinline__ float rcp_(float x){ return __builtin_amdgcn_rcpf(x); }
__device__ __forceinline__ float sigm(float x){ return rcp_(1.f + __expf(-x)); }
__device__ __forceinline__ float tanh_(float x){ return 1.f - 2.f*rcp_(1.f + __expf(2.f*x)); }

// barrier that waits ONLY on LDS ops (no vmcnt/expcnt drain).
__device__ __forceinline__ void bar_lds(){
  asm volatile("s_waitcnt lgkmcnt(0)" ::: "memory");
  __builtin_amdgcn_s_barrier();
  __builtin_amdgcn_sched_barrier(0);   // no hoisting of LDS reads above barrier
}

// --------------------------------------------------------------------------
// cast_x: x[b][t][j] (f32) -> xb[t*256+b][96] (fp16, j>=75 zero)
// --------------------------------------------------------------------------
__global__ __launch_bounds__(256) void cast_x(const float* __restrict__ x,
                                              f16* __restrict__ xb){
  int idx = blockIdx.x*256 + threadIdx.x;        // grid*256 == 131072*96 exact
  int row = idx / KX;
  int j   = idx - row*KX;
  int t   = row >> 8;        // row = t*256 + b
  int b   = row & 255;
  float v = (j < IN_RAW) ? x[((size_t)b*T_ + t)*IN_RAW + j] : 0.f;
  xb[idx] = (f16)v;
}

// --------------------------------------------------------------------------
// cast_w: all weight casts + fused biases. grid*256 == 730624 exact.
// --------------------------------------------------------------------------
__global__ __launch_bounds__(256) void cast_w(
    const float* __restrict__ Wih0, const float* __restrict__ Whh0,
    const float* __restrict__ Wih1, const float* __restrict__ Whh1,
    const float* __restrict__ fcW,
    const float* __restrict__ bih0, const float* __restrict__ bhh0,
    const float* __restrict__ bih1, const float* __restrict__ bhh1,
    f16* __restrict__ W0h, f16* __restrict__ Whh0h, f16* __restrict__ Wih1h,
    f16* __restrict__ Whh1h, f16* __restrict__ fcWh,
    float* __restrict__ bias0, float* __restrict__ bias1){
  int i = blockIdx.x*256 + threadIdx.x;
  if (i < 73728){ int r = i/KX, j = i - r*KX;
    W0h[i] = (f16)((j < IN_RAW) ? Wih0[r*IN_RAW + j] : 0.f); return; }
  i -= 73728;
  if (i < 196608){ Whh0h[i] = (f16)Whh0[i]; return; } i -= 196608;
  if (i < 196608){ Wih1h[i] = (f16)Wih1[i]; return; } i -= 196608;
  if (i < 196608){ Whh1h[i] = (f16)Whh1[i]; return; } i -= 196608;
  if (i < 65536){ fcWh[i] = (f16)fcW[i]; return; } i -= 65536;
  if (i < 768){ bias0[i] = bih0[i] + (i < 512 ? bhh0[i] : 0.f); return; } i -= 768;
  if (i < 768){ bias1[i] = bih1[i] + (i < 512 ? bhh1[i] : 0.f); }
}

// --------------------------------------------------------------------------
// cast_h: h1s f32 [256*256] -> hT fp16
// --------------------------------------------------------------------------
__global__ __launch_bounds__(256) void cast_h(const float* __restrict__ hs,
                                              f16* __restrict__ hT){
  int i = blockIdx.x*256 + threadIdx.x;
  hT[i] = (f16)hs[i];
}

// --------------------------------------------------------------------------
// gemm_k: out[M,N] = A[M,K](fp16) @ W[N,K]^T(fp16) + bias. 256-thread/8-wave
// standalone kernel for the prologue gemm and the fc epilogue.
// --------------------------------------------------------------------------
template<int K, int BN, bool OUTF32>
__global__ __launch_bounds__(256, 2) void gemm_k(const f16* __restrict__ A,
    const f16* __restrict__ W, const float* __restrict__ bias,
    void* __restrict__ outp, const int N){
  constexpr int NT = BN/16;
  const int tid  = threadIdx.x;
  const int wave = tid >> 6, lane = tid & 63;
  const int quad = lane >> 4, l16 = lane & 15;
  const long mbase = (long)blockIdx.x*128 + wave*32;
  const int  nbase = blockIdx.y*BN;
  f32x4 acc[2][NT] = {};
#pragma unroll 2
  for (int kc = 0; kc < K/32; ++kc){
    f16x8 a0 = *(const f16x8*)(A + (mbase +      l16)*K + kc*32 + quad*8);
    f16x8 a1 = *(const f16x8*)(A + (mbase + 16 + l16)*K + kc*32 + quad*8);
#pragma unroll
    for (int nt = 0; nt < NT; ++nt){
      f16x8 b = *(const f16x8*)(W + (long)(nbase + nt*16 + l16)*K + kc*32 + quad*8);
      acc[0][nt] = __builtin_amdgcn_mfma_f32_16x16x32_f16(a0, b, acc[0][nt], 0, 0, 0);
      acc[1][nt] = __builtin_amdgcn_mfma_f32_16x16x32_f16(a1, b, acc[1][nt], 0, 0, 0);
    }
  }
#pragma unroll
  for (int nt = 0; nt < NT; ++nt){
    const int col = nbase + nt*16 + l16;
    const float bv = bias[col];
#pragma unroll
    for (int af = 0; af < 2; ++af){
#pragma unroll
      for (int r = 0; r < 4; ++r){
        const long row = mbase + af*16 + quad*4 + r;   // D row = quad*4 + reg
        float v = acc[af][nt][r] + bv;
        if (OUTF32) ((float*)outp)[row*(long)N + col] = v;
        else        ((f16*)outp)[row*(long)N + col] = (f16)v;
      }
    }
  }
}

// --------------------------------------------------------------------------
// gemm_body128: 512-thread (8-wave) GEMM tile for the fused kernel.
// Block covers 512 rows (2 sequential 256-row tiles) x 128 cols, N=768.
// acc = 2x8 f32x4 = 64 regs -> gemm path stays well under 128 arch VGPRs.
// --------------------------------------------------------------------------
template<int K>
__device__ __forceinline__ void gemm_body128(const f16* __restrict__ A,
    const f16* __restrict__ W, const float* __restrict__ bias,
    f16* __restrict__ out, const int bx, const int by){
  const int tid  = threadIdx.x;
  const int wave = tid >> 6, lane = tid & 63;
  const int quad = lane >> 4, l16 = lane & 15;
  const int nbase = by*128;
#pragma unroll
  for (int mt = 0; mt < 2; ++mt){
    const long mbase = (long)bx*512 + mt*256 + wave*32;
    f32x4 acc[2][8] = {};
#pragma unroll 2
    for (int kc = 0; kc < K/32; ++kc){
      f16x8 a0 = *(const f16x8*)(A + (mbase +      l16)*K + kc*32 + quad*8);
      f16x8 a1 = *(const f16x8*)(A + (mbase + 16 + l16)*K + kc*32 + quad*8);
#pragma unroll
      for (int nt = 0; nt < 8; ++nt){
        f16x8 b = *(const f16x8*)(W + (long)(nbase + nt*16 + l16)*K + kc*32 + quad*8);
        acc[0][nt] = __builtin_amdgcn_mfma_f32_16x16x32_f16(a0, b, acc[0][nt], 0, 0, 0);
        acc[1][nt] = __builtin_amdgcn_mfma_f32_16x16x32_f16(a1, b, acc[1][nt], 0, 0, 0);
      }
    }
#pragma unroll
    for (int nt = 0; nt < 8; ++nt){
      const int col = nbase + nt*16 + l16;
      const float bv = bias[col];
#pragma unroll
      for (int af = 0; af < 2; ++af)
#pragma unroll
        for (int r = 0; r < 4; ++r)
          out[(mbase + af*16 + quad*4 + r)*(long)G_ + col] = (f16)(acc[af][nt][r] + bv);
    }
  }
}

// --------------------------------------------------------------------------
// scan_body: TC steps of one GRU layer, swapped-operand. EXACT r8 body.
// 16 WGs x 512 thr (8 waves); WG owns batch rows [bx*16,+16).
// D[gate rows x batch cols] = Whh(A) * h(B, from swizzled hbuf).
// Wave owns gate rows [w*32,+32) of r/z/n.
//   r,z (all kc): 32 frags = 128 AGPR, pinned via "a" asm constraint
//   n (all kc):   streamed from nlds (128KB, A-frag order, coalesced b128)
// hbuf: byte layout row*512 + ((chunk ^ (row&7))<<4)  -> conflict-free reads.
// Gate inputs xg loaded global->cur after last use; ONE lgkm-only barrier
// per step (global loads/stores remain in flight across it).
// --------------------------------------------------------------------------
__device__ __forceinline__ void scan_body(const f16* __restrict__ xg,
    const f16* __restrict__ Whh, const float* __restrict__ bhh,
    float* __restrict__ hstate, f16* __restrict__ out0,
    const int TC, const int bx){
  __shared__ char  hbufB[2][8192];     // 16 KB: h(t) fp16, XOR-swizzled
  __shared__ f16   nlds[65536];        // 128 KB: full n-gate, A-frag order
  __shared__ float bnlds[256];         // n-gate hidden bias
  const int tid  = threadIdx.x;
  const int wave = tid >> 6, lane = tid & 63;
  const int quad = lane >> 4, l16 = lane & 15;
  const int b0   = bx*16;
  const int jj   = wave*32 + quad*4;   // D-row (hidden) base; s adds 16

  // r,z A-frags: Whh[gate_row][k]; 8 consecutive k per lane -> AGPR-pinned
  f16x8 w[2][2][8];   // [s][g: r,z][kc]
#pragma unroll
  for (int s = 0; s < 2; ++s)
#pragma unroll
    for (int g = 0; g < 2; ++g)
#pragma unroll
      for (int kc = 0; kc < 8; ++kc)
        w[s][g][kc] = *(const f16x8*)(Whh + (size_t)(g*256 + wave*32 + s*16 + l16)*H_ + kc*32 + quad*8);
#pragma unroll
  for (int s = 0; s < 2; ++s)
#pragma unroll
    for (int g = 0; g < 2; ++g)
#pragma unroll
      for (int kc = 0; kc < 8; ++kc)
        asm volatile("" : "+a"(w[s][g][kc]));   // pin in AGPRs

  // stage nlds: piece p = f*64+L, f = wave<<4 | s<<3 | kc; 16B per piece
#pragma unroll
  for (int i = 0; i < 16; ++i){
    const int p  = i*512 + tid;            // 8192 pieces total
    const int f  = p >> 6, L = p & 63;
    const int wv = f >> 4, ss = (f >> 3) & 1, kcc = f & 7;
    const int row = 512 + wv*32 + ss*16 + (L & 15);
    const int k   = kcc*32 + (L >> 4)*8;
    *(f16x8*)&nlds[(size_t)p*8] = *(const f16x8*)(Whh + (size_t)row*H_ + k);
  }
  if (tid < 256) bnlds[tid] = bhh[512 + tid];

  // h state: lane owns (batch=l16, hidden j=jj+s*16+r)
  f32x4 h[2];
#pragma unroll
  for (int s = 0; s < 2; ++s){
    h[s] = *(const f32x4*)(hstate + (size_t)(b0 + l16)*H_ + jj + s*16);
    f16x4 hh;
#pragma unroll
    for (int r = 0; r < 4; ++r) hh[r] = (f16)h[s][r];
    const int ch = wave*4 + s*2 + (quad>>1);                // 16B chunk index
    *(f16x4*)&hbufB[0][l16*512 + ((ch ^ (l16&7))<<4) + ((quad&1)<<3)] = hh;
  }

  // per-lane xg base: row = b0+l16, cols jj + {g*256, s*16}
  const f16* xgl = xg + (size_t)(b0 + l16)*G_ + jj;
  f16x4 cur[6];
#pragma unroll
  for (int s = 0; s < 2; ++s)
#pragma unroll
    for (int g = 0; g < 3; ++g)
      cur[s*3+g] = *(const f16x4*)(xgl + g*256 + s*16);

  __syncthreads();   // one-time full drain: hbuf[0], nlds, bnlds ready

  for (int t = 0; t < TC; ++t){
    const int pb = t & 1;
    f32x4 acc[2][3] = {};
#pragma unroll
    for (int kc = 0; kc < 8; ++kc){
      // B-frag: h[batch=l16][k=kc*32+quad*8], swizzled chunk = kc*4+quad
      f16x8 hf = *(const f16x8*)&hbufB[pb][l16*512 + ((((kc<<2)|quad) ^ (l16&7))<<4)];
#pragma unroll
      for (int s = 0; s < 2; ++s){
        acc[s][0] = __builtin_amdgcn_mfma_f32_16x16x32_f16(w[s][0][kc], hf, acc[s][0], 0,0,0);
        acc[s][1] = __builtin_amdgcn_mfma_f32_16x16x32_f16(w[s][1][kc], hf, acc[s][1], 0,0,0);
        f16x8 nf = *(const f16x8*)&nlds[(size_t)(((wave<<4)|(s<<3)|kc)*64 + lane)*8];
        acc[s][2] = __builtin_amdgcn_mfma_f32_16x16x32_f16(nf, hf, acc[s][2], 0,0,0);
      }
    }
    f16x4 hh[2];
#pragma unroll
    for (int s = 0; s < 2; ++s){
      const f32x4 bnv = *(const f32x4*)&bnlds[jj + s*16];
#pragma unroll
      for (int r = 0; r < 4; ++r){
        float rg = sigm((float)cur[s*3+0][r] + acc[s][0][r]);
        float zg = sigm((float)cur[s*3+1][r] + acc[s][1][r]);
        float ng = tanh_((float)cur[s*3+2][r] + rg*(acc[s][2][r] + bnv[r]));
        float hv = (1.f - zg)*ng + zg*h[s][r];
        h[s][r] = hv;
        hh[s][r] = (f16)hv;
      }
    }
    if (t+1 < TC){  // load t+1 gates into cur (old cur fully consumed above);
      const f16* xn_ = xgl + (size_t)(t+1)*(B_*G_);   // stays in flight across
#pragma unroll                                        // the lgkm-only barrier
      for (int s = 0; s < 2; ++s)
#pragma unroll
        for (int g = 0; g < 3; ++g)
          cur[s*3+g] = *(const f16x4*)(xn_ + g*256 + s*16);
    }
#pragma unroll
    for (int s = 0; s < 2; ++s){
      const int ch = wave*4 + s*2 + (quad>>1);
      *(f16x4*)&hbufB[pb^1][l16*512 + ((ch ^ (l16&7))<<4) + ((quad&1)<<3)] = hh[s];
      if (out0)
        *(f16x4*)(out0 + ((size_t)t*B_ + b0 + l16)*H_ + jj + s*16) = hh[s];
    }
    bar_lds();   // h(t) visible in hbuf[pb^1]; VMEM ops NOT drained
  }

#pragma unroll
  for (int s = 0; s < 2; ++s)
    *(f32x4*)(hstate + (size_t)(b0 + l16)*H_ + jj + s*16) = h[s];
}

// --------------------------------------------------------------------------
// fused: [scan L0] || [scan L1] || [gemm0 next chunk] || [gemm1 prev chunk]
// blocks: [0,16) L0, [16,32) L1, [32,128) gemm0, [128,224) gemm1.
// Gemm block count FIXED at 96/gemm (grid 224 <= 256 CUs, co-residency
// guaranteed); each gemm block iterates TC/32 row-super-tiles (16 row-blocks
// of 512 rows per 32 steps of chunk).
// mask: bit0 L0, bit1 L1, bit2 gemm0, bit3 gemm1.
// --------------------------------------------------------------------------
__global__ __launch_bounds__(512)
__attribute__((amdgpu_waves_per_eu(2, 2)))
void fused(
    const f16* __restrict__ xg0, const f16* __restrict__ Whh0,
    const float* __restrict__ bhh0, float* __restrict__ h0s,
    f16* __restrict__ out0w,
    const f16* __restrict__ xg1, const f16* __restrict__ Whh1,
    const float* __restrict__ bhh1, float* __restrict__ h1s,
    const f16* __restrict__ g0A, const f16* __restrict__ g0W,
    const float* __restrict__ g0b, f16* __restrict__ g0out,
    const f16* __restrict__ g1A, const f16* __restrict__ g1W,
    const float* __restrict__ g1b, f16* __restrict__ g1out,
    const int TC, const int mask){
  const int bid = blockIdx.x;
  if (bid < 16){
    if (!(mask & 1)) return;
    scan_body(xg0, Whh0, bhh0, h0s, out0w, TC, bid);
  } else if (bid < 32){
    if (!(mask & 2)) return;
    scan_body(xg1, Whh1, bhh1, h1s, (f16*)nullptr, TC, bid - 16);
  } else {
    int g = bid - 32;
    const int RBtot = TC/2;              // total 512-row blocks per gemm
    if (g < 96){
      if (!(mask & 4)) return;
      const int rb0 = g % 16, by = g / 16;
      for (int rb = rb0; rb < RBtot; rb += 16)
        gemm_body128<96>(g0A, g0W, g0b, g0out, rb, by);
    } else {
      g -= 96;
      if (!(mask & 8)) return;
      const int rb0 = g % 16, by = g / 16;
      for (int rb = rb0; rb < RBtot; rb += 16)
        gemm_body128<256>(g1A, g1W, g1b, g1out, rb, by);
    }
  }
}

// --------------------------------------------------------------------------
extern "C" void kernel_launch(void* const* d_in, const int* in_sizes, int n_in,
                              void* d_out, int out_size, void* d_ws, size_t ws_size,
                              hipStream_t stream){
  (void)in_sizes; (void)n_in; (void)out_size;
  const float* x    = (const float*)d_in[0];
  const float* Wih0 = (const float*)d_in[1];
  const float* Whh0 = (const float*)d_in[2];
  const float* bih0 = (const float*)d_in[3];
  const float* bhh0 = (const float*)d_in[4];
  const float* Wih1 = (const float*)d_in[5];
  const float* Whh1 = (const float*)d_in[6];
  const float* bih1 = (const float*)d_in[7];
  const float* bhh1 = (const float*)d_in[8];
  const float* fcW  = (const float*)d_in[9];
  const float* fcb  = (const float*)d_in[10];

  char* ws = (char*)d_ws;
  size_t off = 0;
  auto alloc = [&](size_t bytes) -> void* {
    void* p = ws + off; off += (bytes + 255) & ~(size_t)255; return p;
  };
  f16*   xb    = (f16*)  alloc((size_t)MROWS*KX*2);   // 25.2 MB
  f16*   W0h   = (f16*)  alloc((size_t)G_*KX*2);
  f16*   Whh0h = (f16*)  alloc((size_t)G_*H_*2);
  f16*   Wih1h = (f16*)  alloc((size_t)G_*H_*2);
  f16*   Whh1h = (f16*)  alloc((size_t)G_*H_*2);
  f16*   fcWh  = (f16*)  alloc((size_t)H_*H_*2);
  float* bias0 = (float*)alloc(G_*4);
  float* bias1 = (float*)alloc(G_*4);
  float* h0s   = (float*)alloc((size_t)B_*H_*4);      // h-state, both layers
  float* h1s   = (float*)alloc((size_t)B_*H_*4);      //   (adjacent: one memset)
  f16*   hTh   = (f16*)  alloc((size_t)B_*H_*2);
  const size_t fixed = off;

  // chunk size: prefer TC=64 (halves dispatch count / per-dispatch re-init);
  // fall back 32/16/8 if ws is tight. TC=32 reproduces the verified r8 build.
  int TC = 64;
  while (TC > 8 && fixed + (size_t)TC*1835008 + 1024 > ws_size) TC >>= 1;
  f16* xg0[2], *xg1[2], *out0[2];
  xg0[0]  = (f16*)alloc((size_t)TC*B_*G_*2);
  xg0[1]  = (f16*)alloc((size_t)TC*B_*G_*2);
  xg1[0]  = (f16*)alloc((size_t)TC*B_*G_*2);
  xg1[1]  = (f16*)alloc((size_t)TC*B_*G_*2);
  out0[0] = (f16*)alloc((size_t)TC*B_*H_*2);
  out0[1] = (f16*)alloc((size_t)TC*B_*H_*2);
  const int nc = T_ / TC;

  hipMemsetAsync(h0s, 0, (size_t)B_*H_*4*2, stream);  // zero h0s+h1s (adjacent)
  hipLaunchKernelGGL(cast_x, dim3(49152), dim3(256), 0, stream, x, xb);
  hipLaunchKernelGGL(cast_w, dim3(2854), dim3(256), 0, stream,
                     Wih0, Whh0, Wih1, Whh1, fcW, bih0, bhh0, bih1, bhh1,
                     W0h, Whh0h, Wih1h, Whh1h, fcWh, bias0, bias1);

  // prologue: xg0[0] = xb[chunk 0] @ W_ih0^T + bias0
  hipLaunchKernelGGL((gemm_k<96,192,false>), dim3(TC*2,4), dim3(256), 0, stream,
                     xb, W0h, bias0, (void*)xg0[0], G_);

  const dim3 grid(224);
  for (int i = 0; i <= nc + 1; ++i){
    int mask = 0;
    if (i < nc)            mask |= 1;   // L0 scans chunk i
    if (i >= 2)            mask |= 2;   // L1 scans chunk i-2
    if (i + 1 < nc)        mask |= 4;   // gemm0 builds chunk i+1
    if (i >= 1 && i <= nc) mask |= 8;   // gemm1 builds chunk i-1
    hipLaunchKernelGGL(fused, grid, dim3(512), 0, stream,
                       xg0[i&1], Whh0h, bhh0, h0s, out0[i&1],
                       xg1[i&1], Whh1h, bhh1, h1s,
                       xb + (size_t)(i+1)*TC*B_*KX, W0h, bias0, xg0[(i+1)&1],
                       out0[(i+1)&1], Wih1h, bias1, xg1[(i+1)&1],
                       TC, mask);
  }

  // embedding = hT @ fc_W^T + fc_b (f32 out)
  hipLaunchKernelGGL(cast_h, dim3(256), dim3(256), 0, stream, h1s, hTh);
  hipLaunchKernelGGL((gemm_k<256,64,true>), dim3(2,4), dim3(256), 0, stream,
                     hTh, fcWh, fcb, d_out, H_);
}

// Round 14
// 1687.624 us; speedup vs baseline: 1.6688x; 1.0001x over previous
//
#include <hip/hip_runtime.h>
#include <hip/hip_bf16.h>
#include <stdint.h>
#include <stddef.h>

// ---------------------------------------------------------------------------
// GRUEncoder: x[256,512,25,3] f32 -> 2-layer GRU(H=256) -> fc(hT) -> [256,256] f32
//
// Fused pipelined schedule (chunk = TC steps, 2-chunk layer skew):
//   cast_x ; cast_w ; gemm0(chunk0)
//   for i in 0..nc+1:   ONE launch: [scan L0 chunk i] || [scan L1 chunk i-2]
//                                   || [gemm0 chunk i+1] || [gemm1 chunk i-1]
//   fc gemm (hTh written by the final scan dispatch directly)
//
// Dispatch model (r8 + r13 two-point fit): d(TC) = 15.3us init + 2.36us/step.
// Total = (512/TC+2)*init + (512+2TC)*step -> TC=32 is the schedule optimum.
//
// Scan step body = r8 EXACTLY (verified best; 7 perturbations all regressed):
//   - r,z weights pinned in 128 AGPR ("a"); all other VGPRs left FREE
//     (r11/r12: pinning more regs costs scheduling freedom > saved LDS)
//   - n-gate streamed from 128KB LDS; bias from LDS
//   - hbuf XOR-swizzled, double-buffered, ONE lgkm-only barrier per step
//   - xg(t+1) prefetched after gate math, in flight across the barrier
//     (r11: seeding acc from xg exposes the prefetch latency -- never do it)
//   - activations via __builtin_amdgcn_rcpf (r8: +12%)
// r14: TC=32; final L1 scan writes hTh fp16 directly (cast_h launch deleted).
// ---------------------------------------------------------------------------

typedef _Float16 f16;
typedef _Float16 f16x8 __attribute__((ext_vector_type(8)));
typedef _Float16 f16x4 __attribute__((ext_vector_type(4)));
typedef float    f32x4 __attribute__((ext_vector_type(4)));

#define B_      256
#define T_      512
#define H_      256
#define G_      768      // 3*H
#define IN_RAW  75
#define KX      96       // padded input K
#define MROWS   (T_*B_)  // 131072

__device__ __forceinline__ float rcp_(float x){ return __builtin_amdgcn_rcpf(x); }
__device__ __forceinline__ float sigm(float x){ return rcp_(1.f + __expf(-x)); }
__device__ __forceinline__ float tanh_(float x){ return 1.f - 2.f*rcp_(1.f + __expf(2.f*x)); }

// barrier that waits ONLY on LDS ops (no vmcnt/expcnt drain).
__device__ __forceinline__ void bar_lds(){
  asm volatile("s_waitcnt lgkmcnt(0)" ::: "memory");
  __builtin_amdgcn_s_barrier();
  __builtin_amdgcn_sched_barrier(0);   // no hoisting of LDS reads above barrier
}

// --------------------------------------------------------------------------
// cast_x: x[b][t][j] (f32) -> xb[t*256+b][96] (fp16, j>=75 zero)
// --------------------------------------------------------------------------
__global__ __launch_bounds__(256) void cast_x(const float* __restrict__ x,
                                              f16* __restrict__ xb){
  int idx = blockIdx.x*256 + threadIdx.x;        // grid*256 == 131072*96 exact
  int row = idx / KX;
  int j   = idx - row*KX;
  int t   = row >> 8;        // row = t*256 + b
  int b   = row & 255;
  float v = (j < IN_RAW) ? x[((size_t)b*T_ + t)*IN_RAW + j] : 0.f;
  xb[idx] = (f16)v;
}

// --------------------------------------------------------------------------
// cast_w: all weight casts + fused biases. grid*256 == 730624 exact.
// --------------------------------------------------------------------------
__global__ __launch_bounds__(256) void cast_w(
    const float* __restrict__ Wih0, const float* __restrict__ Whh0,
    const float* __restrict__ Wih1, const float* __restrict__ Whh1,
    const float* __restrict__ fcW,
    const float* __restrict__ bih0, const float* __restrict__ bhh0,
    const float* __restrict__ bih1, const float* __restrict__ bhh1,
    f16* __restrict__ W0h, f16* __restrict__ Whh0h, f16* __restrict__ Wih1h,
    f16* __restrict__ Whh1h, f16* __restrict__ fcWh,
    float* __restrict__ bias0, float* __restrict__ bias1){
  int i = blockIdx.x*256 + threadIdx.x;
  if (i < 73728){ int r = i/KX, j = i - r*KX;
    W0h[i] = (f16)((j < IN_RAW) ? Wih0[r*IN_RAW + j] : 0.f); return; }
  i -= 73728;
  if (i < 196608){ Whh0h[i] = (f16)Whh0[i]; return; } i -= 196608;
  if (i < 196608){ Wih1h[i] = (f16)Wih1[i]; return; } i -= 196608;
  if (i < 196608){ Whh1h[i] = (f16)Whh1[i]; return; } i -= 196608;
  if (i < 65536){ fcWh[i] = (f16)fcW[i]; return; } i -= 65536;
  if (i < 768){ bias0[i] = bih0[i] + (i < 512 ? bhh0[i] : 0.f); return; } i -= 768;
  if (i < 768){ bias1[i] = bih1[i] + (i < 512 ? bhh1[i] : 0.f); }
}

// --------------------------------------------------------------------------
// gemm_k: out[M,N] = A[M,K](fp16) @ W[N,K]^T(fp16) + bias. 256-thread/8-wave
// standalone kernel for the prologue gemm and the fc epilogue.
// --------------------------------------------------------------------------
template<int K, int BN, bool OUTF32>
__global__ __launch_bounds__(256, 2) void gemm_k(const f16* __restrict__ A,
    const f16* __restrict__ W, const float* __restrict__ bias,
    void* __restrict__ outp, const int N){
  constexpr int NT = BN/16;
  const int tid  = threadIdx.x;
  const int wave = tid >> 6, lane = tid & 63;
  const int quad = lane >> 4, l16 = lane & 15;
  const long mbase = (long)blockIdx.x*128 + wave*32;
  const int  nbase = blockIdx.y*BN;
  f32x4 acc[2][NT] = {};
#pragma unroll 2
  for (int kc = 0; kc < K/32; ++kc){
    f16x8 a0 = *(const f16x8*)(A + (mbase +      l16)*K + kc*32 + quad*8);
    f16x8 a1 = *(const f16x8*)(A + (mbase + 16 + l16)*K + kc*32 + quad*8);
#pragma unroll
    for (int nt = 0; nt < NT; ++nt){
      f16x8 b = *(const f16x8*)(W + (long)(nbase + nt*16 + l16)*K + kc*32 + quad*8);
      acc[0][nt] = __builtin_amdgcn_mfma_f32_16x16x32_f16(a0, b, acc[0][nt], 0, 0, 0);
      acc[1][nt] = __builtin_amdgcn_mfma_f32_16x16x32_f16(a1, b, acc[1][nt], 0, 0, 0);
    }
  }
#pragma unroll
  for (int nt = 0; nt < NT; ++nt){
    const int col = nbase + nt*16 + l16;
    const float bv = bias[col];
#pragma unroll
    for (int af = 0; af < 2; ++af){
#pragma unroll
      for (int r = 0; r < 4; ++r){
        const long row = mbase + af*16 + quad*4 + r;   // D row = quad*4 + reg
        float v = acc[af][nt][r] + bv;
        if (OUTF32) ((float*)outp)[row*(long)N + col] = v;
        else        ((f16*)outp)[row*(long)N + col] = (f16)v;
      }
    }
  }
}

// --------------------------------------------------------------------------
// gemm_body128: 512-thread (8-wave) GEMM tile for the fused kernel.
// Block covers 512 rows (2 sequential 256-row tiles) x 128 cols, N=768.
// acc = 2x8 f32x4 = 64 regs -> gemm path stays well under 128 arch VGPRs.
// --------------------------------------------------------------------------
template<int K>
__device__ __forceinline__ void gemm_body128(const f16* __restrict__ A,
    const f16* __restrict__ W, const float* __restrict__ bias,
    f16* __restrict__ out, const int bx, const int by){
  const int tid  = threadIdx.x;
  const int wave = tid >> 6, lane = tid & 63;
  const int quad = lane >> 4, l16 = lane & 15;
  const int nbase = by*128;
#pragma unroll
  for (int mt = 0; mt < 2; ++mt){
    const long mbase = (long)bx*512 + mt*256 + wave*32;
    f32x4 acc[2][8] = {};
#pragma unroll 2
    for (int kc = 0; kc < K/32; ++kc){
      f16x8 a0 = *(const f16x8*)(A + (mbase +      l16)*K + kc*32 + quad*8);
      f16x8 a1 = *(const f16x8*)(A + (mbase + 16 + l16)*K + kc*32 + quad*8);
#pragma unroll
      for (int nt = 0; nt < 8; ++nt){
        f16x8 b = *(const f16x8*)(W + (long)(nbase + nt*16 + l16)*K + kc*32 + quad*8);
        acc[0][nt] = __builtin_amdgcn_mfma_f32_16x16x32_f16(a0, b, acc[0][nt], 0, 0, 0);
        acc[1][nt] = __builtin_amdgcn_mfma_f32_16x16x32_f16(a1, b, acc[1][nt], 0, 0, 0);
      }
    }
#pragma unroll
    for (int nt = 0; nt < 8; ++nt){
      const int col = nbase + nt*16 + l16;
      const float bv = bias[col];
#pragma unroll
      for (int af = 0; af < 2; ++af)
#pragma unroll
        for (int r = 0; r < 4; ++r)
          out[(mbase + af*16 + quad*4 + r)*(long)G_ + col] = (f16)(acc[af][nt][r] + bv);
    }
  }
}

// --------------------------------------------------------------------------
// scan_body: TC steps of one GRU layer, swapped-operand. EXACT r8 body.
// 16 WGs x 512 thr (8 waves); WG owns batch rows [bx*16,+16).
// D[gate rows x batch cols] = Whh(A) * h(B, from swizzled hbuf).
// Wave owns gate rows [w*32,+32) of r/z/n.
//   r,z (all kc): 32 frags = 128 AGPR, pinned via "a" asm constraint
//   n (all kc):   streamed from nlds (128KB, A-frag order, coalesced b128)
// hbuf: byte layout row*512 + ((chunk ^ (row&7))<<4)  -> conflict-free reads.
// Gate inputs xg loaded global->cur after last use; ONE lgkm-only barrier
// per step (global loads/stores remain in flight across it).
// hT (optional): final-chunk fp16 copy of the terminal h-state.
// --------------------------------------------------------------------------
__device__ __forceinline__ void scan_body(const f16* __restrict__ xg,
    const f16* __restrict__ Whh, const float* __restrict__ bhh,
    float* __restrict__ hstate, f16* __restrict__ out0,
    f16* __restrict__ hT, const int TC, const int bx){
  __shared__ char  hbufB[2][8192];     // 16 KB: h(t) fp16, XOR-swizzled
  __shared__ f16   nlds[65536];        // 128 KB: full n-gate, A-frag order
  __shared__ float bnlds[256];         // n-gate hidden bias
  const int tid  = threadIdx.x;
  const int wave = tid >> 6, lane = tid & 63;
  const int quad = lane >> 4, l16 = lane & 15;
  const int b0   = bx*16;
  const int jj   = wave*32 + quad*4;   // D-row (hidden) base; s adds 16

  // r,z A-frags: Whh[gate_row][k]; 8 consecutive k per lane -> AGPR-pinned
  f16x8 w[2][2][8];   // [s][g: r,z][kc]
#pragma unroll
  for (int s = 0; s < 2; ++s)
#pragma unroll
    for (int g = 0; g < 2; ++g)
#pragma unroll
      for (int kc = 0; kc < 8; ++kc)
        w[s][g][kc] = *(const f16x8*)(Whh + (size_t)(g*256 + wave*32 + s*16 + l16)*H_ + kc*32 + quad*8);
#pragma unroll
  for (int s = 0; s < 2; ++s)
#pragma unroll
    for (int g = 0; g < 2; ++g)
#pragma unroll
      for (int kc = 0; kc < 8; ++kc)
        asm volatile("" : "+a"(w[s][g][kc]));   // pin in AGPRs

  // stage nlds: piece p = f*64+L, f = wave<<4 | s<<3 | kc; 16B per piece
#pragma unroll
  for (int i = 0; i < 16; ++i){
    const int p  = i*512 + tid;            // 8192 pieces total
    const int f  = p >> 6, L = p & 63;
    const int wv = f >> 4, ss = (f >> 3) & 1, kcc = f & 7;
    const int row = 512 + wv*32 + ss*16 + (L & 15);
    const int k   = kcc*32 + (L >> 4)*8;
    *(f16x8*)&nlds[(size_t)p*8] = *(const f16x8*)(Whh + (size_t)row*H_ + k);
  }
  if (tid < 256) bnlds[tid] = bhh[512 + tid];

  // h state: lane owns (batch=l16, hidden j=jj+s*16+r)
  f32x4 h[2];
#pragma unroll
  for (int s = 0; s < 2; ++s){
    h[s] = *(const f32x4*)(hstate + (size_t)(b0 + l16)*H_ + jj + s*16);
    f16x4 hh;
#pragma unroll
    for (int r = 0; r < 4; ++r) hh[r] = (f16)h[s][r];
    const int ch = wave*4 + s*2 + (quad>>1);                // 16B chunk index
    *(f16x4*)&hbufB[0][l16*512 + ((ch ^ (l16&7))<<4) + ((quad&1)<<3)] = hh;
  }

  // per-lane xg base: row = b0+l16, cols jj + {g*256, s*16}
  const f16* xgl = xg + (size_t)(b0 + l16)*G_ + jj;
  f16x4 cur[6];
#pragma unroll
  for (int s = 0; s < 2; ++s)
#pragma unroll
    for (int g = 0; g < 3; ++g)
      cur[s*3+g] = *(const f16x4*)(xgl + g*256 + s*16);

  __syncthreads();   // one-time full drain: hbuf[0], nlds, bnlds ready

  for (int t = 0; t < TC; ++t){
    const int pb = t & 1;
    f32x4 acc[2][3] = {};
#pragma unroll
    for (int kc = 0; kc < 8; ++kc){
      // B-frag: h[batch=l16][k=kc*32+quad*8], swizzled chunk = kc*4+quad
      f16x8 hf = *(const f16x8*)&hbufB[pb][l16*512 + ((((kc<<2)|quad) ^ (l16&7))<<4)];
#pragma unroll
      for (int s = 0; s < 2; ++s){
        acc[s][0] = __builtin_amdgcn_mfma_f32_16x16x32_f16(w[s][0][kc], hf, acc[s][0], 0,0,0);
        acc[s][1] = __builtin_amdgcn_mfma_f32_16x16x32_f16(w[s][1][kc], hf, acc[s][1], 0,0,0);
        f16x8 nf = *(const f16x8*)&nlds[(size_t)(((wave<<4)|(s<<3)|kc)*64 + lane)*8];
        acc[s][2] = __builtin_amdgcn_mfma_f32_16x16x32_f16(nf, hf, acc[s][2], 0,0,0);
      }
    }
    f16x4 hh[2];
#pragma unroll
    for (int s = 0; s < 2; ++s){
      const f32x4 bnv = *(const f32x4*)&bnlds[jj + s*16];
#pragma unroll
      for (int r = 0; r < 4; ++r){
        float rg = sigm((float)cur[s*3+0][r] + acc[s][0][r]);
        float zg = sigm((float)cur[s*3+1][r] + acc[s][1][r]);
        float ng = tanh_((float)cur[s*3+2][r] + rg*(acc[s][2][r] + bnv[r]));
        float hv = (1.f - zg)*ng + zg*h[s][r];
        h[s][r] = hv;
        hh[s][r] = (f16)hv;
      }
    }
    if (t+1 < TC){  // load t+1 gates into cur (old cur fully consumed above);
      const f16* xn_ = xgl + (size_t)(t+1)*(B_*G_);   // stays in flight across
#pragma unroll                                        // the lgkm-only barrier
      for (int s = 0; s < 2; ++s)
#pragma unroll
        for (int g = 0; g < 3; ++g)
          cur[s*3+g] = *(const f16x4*)(xn_ + g*256 + s*16);
    }
#pragma unroll
    for (int s = 0; s < 2; ++s){
      const int ch = wave*4 + s*2 + (quad>>1);
      *(f16x4*)&hbufB[pb^1][l16*512 + ((ch ^ (l16&7))<<4) + ((quad&1)<<3)] = hh[s];
      if (out0)
        *(f16x4*)(out0 + ((size_t)t*B_ + b0 + l16)*H_ + jj + s*16) = hh[s];
    }
    bar_lds();   // h(t) visible in hbuf[pb^1]; VMEM ops NOT drained
  }

#pragma unroll
  for (int s = 0; s < 2; ++s){
    *(f32x4*)(hstate + (size_t)(b0 + l16)*H_ + jj + s*16) = h[s];
    if (hT){   // final chunk: emit fp16 hT directly (replaces cast_h launch)
      f16x4 hh;
#pragma unroll
      for (int r = 0; r < 4; ++r) hh[r] = (f16)h[s][r];
      *(f16x4*)(hT + (size_t)(b0 + l16)*H_ + jj + s*16) = hh;
    }
  }
}

// --------------------------------------------------------------------------
// fused: [scan L0] || [scan L1] || [gemm0 next chunk] || [gemm1 prev chunk]
// blocks: [0,16) L0, [16,32) L1, [32,32+3TC) gemm0, [32+3TC,32+6TC) gemm1.
// mask: bit0 L0, bit1 L1, bit2 gemm0, bit3 gemm1, bit4 L1-final (write hT).
// grid = 32+6TC (=224 at TC=32).
// --------------------------------------------------------------------------
__global__ __launch_bounds__(512)
__attribute__((amdgpu_waves_per_eu(2, 2)))
void fused(
    const f16* __restrict__ xg0, const f16* __restrict__ Whh0,
    const float* __restrict__ bhh0, float* __restrict__ h0s,
    f16* __restrict__ out0w,
    const f16* __restrict__ xg1, const f16* __restrict__ Whh1,
    const float* __restrict__ bhh1, float* __restrict__ h1s,
    f16* __restrict__ hTh,
    const f16* __restrict__ g0A, const f16* __restrict__ g0W,
    const float* __restrict__ g0b, f16* __restrict__ g0out,
    const f16* __restrict__ g1A, const f16* __restrict__ g1W,
    const float* __restrict__ g1b, f16* __restrict__ g1out,
    const int TC, const int mask){
  const int bid = blockIdx.x;
  if (bid < 16){
    if (!(mask & 1)) return;
    scan_body(xg0, Whh0, bhh0, h0s, out0w, (f16*)nullptr, TC, bid);
  } else if (bid < 32){
    if (!(mask & 2)) return;
    scan_body(xg1, Whh1, bhh1, h1s, (f16*)nullptr,
              (mask & 16) ? hTh : (f16*)nullptr, TC, bid - 16);
  } else {
    int g = bid - 32;
    const int RB = TC/2;                 // 512-row blocks per gemm
    if (g < 3*TC){
      if (!(mask & 4)) return;
      gemm_body128<96>(g0A, g0W, g0b, g0out, g % RB, g / RB);
    } else {
      g -= 3*TC;
      if (!(mask & 8)) return;
      gemm_body128<256>(g1A, g1W, g1b, g1out, g % RB, g / RB);
    }
  }
}

// --------------------------------------------------------------------------
extern "C" void kernel_launch(void* const* d_in, const int* in_sizes, int n_in,
                              void* d_out, int out_size, void* d_ws, size_t ws_size,
                              hipStream_t stream){
  (void)in_sizes; (void)n_in; (void)out_size;
  const float* x    = (const float*)d_in[0];
  const float* Wih0 = (const float*)d_in[1];
  const float* Whh0 = (const float*)d_in[2];
  const float* bih0 = (const float*)d_in[3];
  const float* bhh0 = (const float*)d_in[4];
  const float* Wih1 = (const float*)d_in[5];
  const float* Whh1 = (const float*)d_in[6];
  const float* bih1 = (const float*)d_in[7];
  const float* bhh1 = (const float*)d_in[8];
  const float* fcW  = (const float*)d_in[9];
  const float* fcb  = (const float*)d_in[10];

  char* ws = (char*)d_ws;
  size_t off = 0;
  auto alloc = [&](size_t bytes) -> void* {
    void* p = ws + off; off += (bytes + 255) & ~(size_t)255; return p;
  };
  f16*   xb    = (f16*)  alloc((size_t)MROWS*KX*2);   // 25.2 MB
  f16*   W0h   = (f16*)  alloc((size_t)G_*KX*2);
  f16*   Whh0h = (f16*)  alloc((size_t)G_*H_*2);
  f16*   Wih1h = (f16*)  alloc((size_t)G_*H_*2);
  f16*   Whh1h = (f16*)  alloc((size_t)G_*H_*2);
  f16*   fcWh  = (f16*)  alloc((size_t)H_*H_*2);
  float* bias0 = (float*)alloc(G_*4);
  float* bias1 = (float*)alloc(G_*4);
  float* h0s   = (float*)alloc((size_t)B_*H_*4);      // h-state, both layers
  float* h1s   = (float*)alloc((size_t)B_*H_*4);      //   (adjacent: one memset)
  f16*   hTh   = (f16*)  alloc((size_t)B_*H_*2);
  const size_t fixed = off;

  // TC=32: optimum of the measured dispatch model d(TC)=15.3us+2.36us*TC.
  int TC = 32;
  while (TC > 8 && fixed + (size_t)TC*1835008 + 1024 > ws_size) TC >>= 1;
  f16* xg0[2], *xg1[2], *out0[2];
  xg0[0]  = (f16*)alloc((size_t)TC*B_*G_*2);
  xg0[1]  = (f16*)alloc((size_t)TC*B_*G_*2);
  xg1[0]  = (f16*)alloc((size_t)TC*B_*G_*2);
  xg1[1]  = (f16*)alloc((size_t)TC*B_*G_*2);
  out0[0] = (f16*)alloc((size_t)TC*B_*H_*2);
  out0[1] = (f16*)alloc((size_t)TC*B_*H_*2);
  const int nc = T_ / TC;

  hipMemsetAsync(h0s, 0, (size_t)B_*H_*4*2, stream);  // zero h0s+h1s (adjacent)
  hipLaunchKernelGGL(cast_x, dim3(49152), dim3(256), 0, stream, x, xb);
  hipLaunchKernelGGL(cast_w, dim3(2854), dim3(256), 0, stream,
                     Wih0, Whh0, Wih1, Whh1, fcW, bih0, bhh0, bih1, bhh1,
                     W0h, Whh0h, Wih1h, Whh1h, fcWh, bias0, bias1);

  // prologue: xg0[0] = xb[chunk 0] @ W_ih0^T + bias0
  hipLaunchKernelGGL((gemm_k<96,192,false>), dim3(TC*2,4), dim3(256), 0, stream,
                     xb, W0h, bias0, (void*)xg0[0], G_);

  const dim3 grid(32 + 6*TC);
  for (int i = 0; i <= nc + 1; ++i){
    int mask = 0;
    if (i < nc)            mask |= 1;    // L0 scans chunk i
    if (i >= 2)            mask |= 2;    // L1 scans chunk i-2
    if (i + 1 < nc)        mask |= 4;    // gemm0 builds chunk i+1
    if (i >= 1 && i <= nc) mask |= 8;    // gemm1 builds chunk i-1
    if (i == nc + 1)       mask |= 16;   // L1 final chunk -> write hTh
    hipLaunchKernelGGL(fused, grid, dim3(512), 0, stream,
                       xg0[i&1], Whh0h, bhh0, h0s, out0[i&1],
                       xg1[i&1], Whh1h, bhh1, h1s, hTh,
                       xb + (size_t)(i+1)*TC*B_*KX, W0h, bias0, xg0[(i+1)&1],
                       out0[(i+1)&1], Wih1h, bias1, xg1[(i+1)&1],
                       TC, mask);
  }

  // embedding = hT @ fc_W^T + fc_b (f32 out)
  hipLaunchKernelGGL((gemm_k<256,64,true>), dim3(2,4), dim3(256), 0, stream,
                     hTh, fcWh, fcb, d_out, H_);
}